// Round 1
// baseline (5027.769 us; speedup 1.0000x reference)
//
#include <hip/hip_runtime.h>

typedef __attribute__((ext_vector_type(8))) short s16x8;
typedef __attribute__((ext_vector_type(4))) short s16x4;
typedef __attribute__((ext_vector_type(4))) float f32x4;

__device__ __forceinline__ unsigned short f2bf(float f){
    union{float f;unsigned u;}v; v.f=f;
    unsigned u=v.u;
    unsigned r=(u+0x7fffu+((u>>16)&1u))>>16;
    return (unsigned short)r;
}
__device__ __forceinline__ float bf2f(unsigned short s){
    union{unsigned u;float f;}v; v.u=((unsigned)s)<<16; return v.f;
}

#define ATT_SCALE 0.125f

// ---------------------------------------------------------------------------
// Generic bf16 MFMA GEMM: C = [scale] * (A @ B) [+bias] [+res]
// A: (M,K) bf16 row-major, stride lda
// B: BTRANS ? (N,K) bf16 row-major (already transposed, stage like A)
//           : (K,N) row-major, f32 (BF32) or bf16, transposed into LDS
// z batching: base += zb*Sb + zh*Sh  (zb=z/zH, zh=z%zH)
// ---------------------------------------------------------------------------
template<int BM,int BN,int WN,bool BF32,bool BTRANS,bool BIAS,bool RES,bool OBF16,bool SCL>
__global__ __launch_bounds__(256) void gemm_k(
    const unsigned short* __restrict__ A,
    const void* __restrict__ Bp,
    const float* __restrict__ bias,
    const float* __restrict__ res,
    void* __restrict__ Cp,
    int M,int N,int K,int lda,int ldb,int ldc,
    long aSb,long aSh,long bSb,long bSh,long cSb,long cSh,int zH)
{
    constexpr int BK=64, PAD=24, LDS_=BK+PAD;   // 88 elems = 176B rows (16B aligned)
    constexpr int WM = 4/WN;
    constexpr int WTM = BM/WM, WTN = BN/WN;
    constexpr int FM = WTM/16, FN = WTN/16;
    __shared__ unsigned short As[BM*LDS_];
    __shared__ unsigned short Bs[BN*LDS_];

    const int t = threadIdx.x;
    const int w = t>>6, lane = t&63;
    const int wr = w / WN, wc = w % WN;
    const int lr = lane & 15, lg = lane >> 4;

    const int z = blockIdx.z;
    const int zb = z / zH, zh = z % zH;
    const long row0 = (long)blockIdx.y*BM;
    const long col0 = (long)blockIdx.x*BN;

    const unsigned short* Ab = A + zb*aSb + zh*aSh;

    f32x4 acc[FM][FN];
    #pragma unroll
    for(int i=0;i<FM;i++)
        #pragma unroll
        for(int j=0;j<FN;j++) acc[i][j] = f32x4{0.f,0.f,0.f,0.f};

    const int NT = K/BK;
    for(int kt=0; kt<NT; ++kt){
        const int kb = kt*BK;
        { // stage A (bf16, row-major, 4 elems per thread per pass)
            constexpr int PASS = BM*BK/(256*4);
            #pragma unroll
            for(int p=0;p<PASS;p++){
                int idx = (p*256+t)*4;
                int r = idx/BK, c = idx%BK;
                *(s16x4*)&As[r*LDS_+c] = *(const s16x4*)(Ab + (row0+r)*lda + kb + c);
            }
        }
        if constexpr (BTRANS){ // B already (N,K) bf16: stage like A
            const unsigned short* Bb = (const unsigned short*)Bp + zb*bSb + zh*bSh;
            constexpr int PASS = BN*BK/(256*4);
            #pragma unroll
            for(int p=0;p<PASS;p++){
                int idx=(p*256+t)*4; int r=idx/BK, c=idx%BK;
                *(s16x4*)&Bs[r*LDS_+c] = *(const s16x4*)(Bb + (col0+r)*ldb + kb + c);
            }
        } else { // B (K,N): transpose into Bs[n][k], converting f32->bf16 if needed
            constexpr int TPB = 256/BN;
            constexpr int KC  = BK/TPB;
            const int n = t % BN, k0 = (t/BN)*KC;
            #pragma unroll
            for(int j0=0;j0<KC;j0+=8){
                s16x8 pk;
                #pragma unroll
                for(int i=0;i<8;i++){
                    const long gk = (long)kb + k0 + j0 + i;
                    if constexpr (BF32){
                        const float* Bb = (const float*)Bp + zb*bSb + zh*bSh;
                        pk[i] = (short)f2bf(Bb[gk*ldb + col0 + n]);
                    } else {
                        const unsigned short* Bb = (const unsigned short*)Bp + zb*bSb + zh*bSh;
                        pk[i] = (short)Bb[gk*ldb + col0 + n];
                    }
                }
                *(s16x8*)&Bs[n*LDS_ + k0 + j0] = pk;
            }
        }
        __syncthreads();
        const unsigned short* Ar = &As[(wr*WTM + lr)*LDS_ + lg*8];
        const unsigned short* Br = &Bs[(wc*WTN + lr)*LDS_ + lg*8];
        #pragma unroll
        for(int kk=0;kk<BK/32;kk++){
            s16x8 af[FM], bfv[FN];
            #pragma unroll
            for(int i=0;i<FM;i++) af[i]  = *(const s16x8*)(Ar + i*16*LDS_ + kk*32);
            #pragma unroll
            for(int j=0;j<FN;j++) bfv[j] = *(const s16x8*)(Br + j*16*LDS_ + kk*32);
            #pragma unroll
            for(int i=0;i<FM;i++)
                #pragma unroll
                for(int j=0;j<FN;j++)
                    acc[i][j] = __builtin_amdgcn_mfma_f32_16x16x32_bf16(af[i],bfv[j],acc[i][j],0,0,0);
        }
        __syncthreads();
    }
    // epilogue: C/D layout col=lane&15, row=(lane>>4)*4+r (guide-verified)
    #pragma unroll
    for(int i=0;i<FM;i++){
        #pragma unroll
        for(int j=0;j<FN;j++){
            #pragma unroll
            for(int r=0;r<4;r++){
                long grow = row0 + wr*WTM + i*16 + lg*4 + r;
                long gcol = col0 + wc*WTN + j*16 + lr;
                float vv = acc[i][j][r];
                if constexpr (SCL)  vv *= ATT_SCALE;
                if constexpr (BIAS) vv += bias[gcol];
                if constexpr (RES)  vv += res[grow*ldc + gcol];
                long cidx = zb*cSb + zh*cSh + grow*ldc + gcol;
                if constexpr (OBF16) ((unsigned short*)Cp)[cidx] = f2bf(vv);
                else                 ((float*)Cp)[cidx] = vv;
            }
        }
    }
}

// ---------------------------------------------------------------------------
// LayerNorm over D=1024 (one block per row). GATHER: src row = tok_emb[tok[row]].
// ---------------------------------------------------------------------------
template<bool GATHER, bool OBF16>
__global__ __launch_bounds__(256) void ln_k(const float* __restrict__ in,
    const float* __restrict__ w, const float* __restrict__ b,
    void* __restrict__ out, const int* __restrict__ tok)
{
    const int row = blockIdx.x, t = threadIdx.x;
    const float* src;
    if constexpr (GATHER) src = in + (long)tok[row]*1024;
    else                  src = in + (long)row*1024;
    const int c = t*4;
    f32x4 xv = *(const f32x4*)(src + c);
    float s  = xv[0]+xv[1]+xv[2]+xv[3];
    float qq = xv[0]*xv[0]+xv[1]*xv[1]+xv[2]*xv[2]+xv[3]*xv[3];
    #pragma unroll
    for(int m=32;m;m>>=1){ s += __shfl_xor(s,m); qq += __shfl_xor(qq,m); }
    __shared__ float rs_[4], rq_[4];
    if((t&63)==0){ rs_[t>>6]=s; rq_[t>>6]=qq; }
    __syncthreads();
    s  = rs_[0]+rs_[1]+rs_[2]+rs_[3];
    qq = rq_[0]+rq_[1]+rq_[2]+rq_[3];
    const float mu = s*(1.f/1024.f);
    const float rstd = rsqrtf(qq*(1.f/1024.f)-mu*mu + 1e-5f);
    f32x4 wv = *(const f32x4*)(w+c), bv = *(const f32x4*)(b+c);
    if constexpr (OBF16){
        s16x4 ov;
        #pragma unroll
        for(int i=0;i<4;i++) ov[i]=(short)f2bf((xv[i]-mu)*rstd*wv[i]+bv[i]);
        *(s16x4*)((unsigned short*)out + (long)row*1024 + c) = ov;
    } else {
        f32x4 ov;
        #pragma unroll
        for(int i=0;i<4;i++) ov[i]=(xv[i]-mu)*rstd*wv[i]+bv[i];
        *(f32x4*)((float*)out + (long)row*1024 + c) = ov;
    }
}

// ---------------------------------------------------------------------------
// In-place row softmax on bf16 scores; row = 2048 elems, one block per row.
// ---------------------------------------------------------------------------
__global__ __launch_bounds__(256) void softmax_k(unsigned short* __restrict__ p)
{
    const long row = blockIdx.x;
    unsigned short* rp = p + row*2048;
    const int t = threadIdx.x;
    s16x8 sv = *(s16x8*)(rp + t*8);
    float v[8]; float m=-1e30f;
    #pragma unroll
    for(int i=0;i<8;i++){ v[i]=bf2f((unsigned short)sv[i]); m=fmaxf(m,v[i]); }
    #pragma unroll
    for(int mm=32;mm;mm>>=1) m = fmaxf(m, __shfl_xor(m,mm));
    __shared__ float rm[4], rsum[4];
    if((t&63)==0) rm[t>>6]=m;
    __syncthreads();
    m = fmaxf(fmaxf(rm[0],rm[1]),fmaxf(rm[2],rm[3]));
    float s=0.f;
    #pragma unroll
    for(int i=0;i<8;i++){ v[i]=__expf(v[i]-m); s+=v[i]; }
    #pragma unroll
    for(int mm=32;mm;mm>>=1) s += __shfl_xor(s,mm);
    if((t&63)==0) rsum[t>>6]=s;
    __syncthreads();
    s = rsum[0]+rsum[1]+rsum[2]+rsum[3];
    const float inv = 1.f/s;
    s16x8 ov;
    #pragma unroll
    for(int i=0;i<8;i++) ov[i]=(short)f2bf(v[i]*inv);
    *(s16x8*)(rp + t*8) = ov;
}

// ---------------------------------------------------------------------------
// GeGLU: ff[r][c] = gelu_exact(gv[r][c]) * gv[r][c+4096]; gv (4096,8192) f32
// ---------------------------------------------------------------------------
__global__ __launch_bounds__(256) void gelu_k(const float* __restrict__ gv,
                                              unsigned short* __restrict__ ff)
{
    const long total4 = (long)4096*4096/4;
    for(long i4 = (long)blockIdx.x*256+threadIdx.x; i4<total4; i4 += (long)gridDim.x*256){
        long idx = i4*4;
        long r = idx>>12; int c = (int)(idx&4095);
        f32x4 g  = *(const f32x4*)(gv + r*8192 + c);
        f32x4 vl = *(const f32x4*)(gv + r*8192 + 4096 + c);
        s16x4 ov;
        #pragma unroll
        for(int i=0;i<4;i++){
            float gg=g[i];
            float ge = 0.5f*gg*(1.f+erff(gg*0.70710678118654752f));
            ov[i]=(short)f2bf(ge*vl[i]);
        }
        *(s16x4*)(ff+idx)=ov;
    }
}

// ---------------------------------------------------------------------------
extern "C" void kernel_launch(void* const* d_in, const int* in_sizes, int n_in,
                              void* d_out, int out_size, void* d_ws, size_t ws_size,
                              hipStream_t stream)
{
    const int*   tokens  = (const int*)  d_in[0];
    const float* tok_emb = (const float*)d_in[1];
    const float* ln_e_w  = (const float*)d_in[2];
    const float* ln_e_b  = (const float*)d_in[3];
    const float* ln1_w   = (const float*)d_in[4];
    const float* ln1_b   = (const float*)d_in[5];
    const float* wq      = (const float*)d_in[6];
    const float* bq      = (const float*)d_in[7];
    const float* wk      = (const float*)d_in[8];
    const float* bk      = (const float*)d_in[9];
    const float* wv      = (const float*)d_in[10];
    const float* bv      = (const float*)d_in[11];
    const float* wo      = (const float*)d_in[12];
    const float* bo      = (const float*)d_in[13];
    const float* ln2_w   = (const float*)d_in[14];
    const float* ln2_b   = (const float*)d_in[15];
    const float* w1      = (const float*)d_in[16];
    const float* b1      = (const float*)d_in[17];
    const float* w2      = (const float*)d_in[18];
    const float* b2      = (const float*)d_in[19];
    const float* lnf_w   = (const float*)d_in[20];
    const float* lnf_b   = (const float*)d_in[21];
    const float* w_out   = (const float*)d_in[22];
    const float* b_out   = (const float*)d_in[23];

    const int S=2048, D=1024, H=16;
    const long SD = (long)S*D;           // per-batch stride in q/k/v/o/x
    const long SS = (long)S*S;           // per-head score stride
    const long HSS = (long)H*SS;
    const long DD = (long)D*D;

    // d_out scratch: scores (bf16, 256MB) + gv (f32, 128MB); out total 500MB
    unsigned short* scores = (unsigned short*)d_out;
    float* gv = (float*)((char*)d_out + 268435456ull);

    // small buffers
    float* x; unsigned short *h,*q,*k,*v,*o,*ff;
    const size_t need = 16777216ull + 5ull*8388608ull + 33554432ull; // 92.3MB
    if (ws_size >= need){
        char* p=(char*)d_ws;
        x=(float*)p;            p+=16777216;
        h=(unsigned short*)p;   p+=8388608;
        q=(unsigned short*)p;   p+=8388608;
        k=(unsigned short*)p;   p+=8388608;
        v=(unsigned short*)p;   p+=8388608;
        o=(unsigned short*)p;   p+=8388608;
        ff=(unsigned short*)p;
    } else {
        h=(unsigned short*)d_ws;                       // h must live outside d_out
        char* p=(char*)d_out + 402653184ull;           // tail after scores+gv
        x=(float*)p;            p+=16777216;
        q=(unsigned short*)p;   p+=8388608;
        k=(unsigned short*)p;   p+=8388608;
        v=(unsigned short*)p;   p+=8388608;
        o=(unsigned short*)p;   p+=8388608;
        ff=(unsigned short*)p;
    }

    const dim3 blk(256,1,1);
    const dim3 g_d   (8,  32, 1);    // (4096 x 1024) GEMMs
    const dim3 g_qk  (16, 16, 32);   // per (b,h) 2048x2048
    const dim3 g_pv  (1,  16, 32);   // per (b,h) 2048x64
    const dim3 g_ff1 (64, 32, 1);    // 4096 x 8192
    const dim3 g_outp(250,32, 1);    // 4096 x 32000

    // embed + ln_e -> x (f32)
    ln_k<true,false><<<4096,blk,0,stream>>>(tok_emb, ln_e_w, ln_e_b, x, tokens);

    for(int l=0;l<4;l++){
        ln_k<false,true><<<4096,blk,0,stream>>>(x, ln1_w+l*D, ln1_b+l*D, h, nullptr);
        // QKV projections (bf16 out)
        gemm_k<128,128,2,true,false,true,false,true,false><<<g_d,blk,0,stream>>>(
            h, wq+l*DD, bq+l*D, nullptr, q, 4096,1024,1024, 1024,1024,1024, 0,0,0,0,0,0, 1);
        gemm_k<128,128,2,true,false,true,false,true,false><<<g_d,blk,0,stream>>>(
            h, wk+l*DD, bk+l*D, nullptr, k, 4096,1024,1024, 1024,1024,1024, 0,0,0,0,0,0, 1);
        gemm_k<128,128,2,true,false,true,false,true,false><<<g_d,blk,0,stream>>>(
            h, wv+l*DD, bv+l*D, nullptr, v, 4096,1024,1024, 1024,1024,1024, 0,0,0,0,0,0, 1);
        // scores = scale * q @ k^T   (B already "transposed": k is (N=S, K=64) row-major)
        gemm_k<128,128,2,false,true,false,false,true,true><<<g_qk,blk,0,stream>>>(
            q, k, nullptr, nullptr, scores, 2048,2048,64, 1024,1024,2048,
            SD,64, SD,64, HSS,SS, H);
        softmax_k<<<65536,blk,0,stream>>>(scores);
        // o = P @ V
        gemm_k<128,64,1,false,false,false,false,true,false><<<g_pv,blk,0,stream>>>(
            scores, v, nullptr, nullptr, o, 2048,64,2048, 2048,1024,1024,
            HSS,SS, SD,64, SD,64, H);
        // x += o @ wo + bo
        gemm_k<128,128,2,true,false,true,true,false,false><<<g_d,blk,0,stream>>>(
            o, wo+l*DD, bo+l*D, x, x, 4096,1024,1024, 1024,1024,1024, 0,0,0,0,0,0, 1);
        // FFN
        ln_k<false,true><<<4096,blk,0,stream>>>(x, ln2_w+l*D, ln2_b+l*D, h, nullptr);
        gemm_k<128,128,2,true,false,true,false,false,false><<<g_ff1,blk,0,stream>>>(
            h, w1+(long)l*D*8192, b1+(long)l*8192, nullptr, gv, 4096,8192,1024,
            1024,8192,8192, 0,0,0,0,0,0, 1);
        gelu_k<<<4096,blk,0,stream>>>(gv, ff);
        gemm_k<128,128,2,true,false,true,true,false,false><<<g_d,blk,0,stream>>>(
            ff, w2+(long)l*4096*D, b2+l*D, x, x, 4096,1024,4096, 4096,1024,1024, 0,0,0,0,0,0, 1);
    }

    ln_k<false,true><<<4096,blk,0,stream>>>(x, lnf_w, lnf_b, h, nullptr);
    gemm_k<128,128,2,true,false,true,false,false,false><<<g_outp,blk,0,stream>>>(
        h, w_out, b_out, nullptr, (float*)d_out, 4096,32000,1024, 1024,32000,32000,
        0,0,0,0,0,0, 1);
}

// Round 2
// 3112.627 us; speedup vs baseline: 1.6153x; 1.6153x over previous
//
#include <hip/hip_runtime.h>

typedef __attribute__((ext_vector_type(8))) short s16x8;
typedef __attribute__((ext_vector_type(4))) short s16x4;
typedef __attribute__((ext_vector_type(4))) float f32x4;

__device__ __forceinline__ unsigned short f2bf(float f){
    union{float f;unsigned u;}v; v.f=f;
    unsigned u=v.u;
    unsigned r=(u+0x7fffu+((u>>16)&1u))>>16;
    return (unsigned short)r;
}
__device__ __forceinline__ float bf2f(unsigned short s){
    union{unsigned u;float f;}v; v.u=((unsigned)s)<<16; return v.f;
}

__device__ __forceinline__ void gl16(const void* g, void* l){
    __builtin_amdgcn_global_load_lds(
        (const __attribute__((address_space(1))) void*)g,
        (__attribute__((address_space(3))) void*)l, 16, 0, 0);
}

#define ATT_SCALE 0.125f

// ---------------------------------------------------------------------------
// Fast GEMM (m97 structure): A (M,K) bf16 rm, B (N,K) bf16 rm, both staged via
// global_load_lds width=16 into linear LDS [rows][64]. BK=64.
// ---------------------------------------------------------------------------
template<int BM,int BN,int WN,bool BIAS,bool RES,bool OBF16,bool SCL,bool SWAP,bool GEGLU>
__global__ __launch_bounds__(256) void gemm_bt(
    const unsigned short* __restrict__ A,
    const unsigned short* __restrict__ B,
    const unsigned short* __restrict__ B2,
    const float* __restrict__ bias,
    const float* __restrict__ res,
    void* __restrict__ Cp,
    int K,int lda,int ldb,int ldc,
    long aSb,long aSh,long bSb,long bSh,long cSb,long cSh,int zH)
{
    constexpr int BK=64;
    constexpr int WM=4/WN, WTM=BM/WM, WTN=BN/WN;
    constexpr int FM=WTM/16, FN=WTN/16;
    constexpr int CA=BM/8, CB=BN/8;
    __shared__ __align__(16) unsigned short As[BM*BK];
    __shared__ __align__(16) unsigned short Bs[BN*BK*(GEGLU?2:1)];

    const int t=threadIdx.x, w=t>>6, lane=t&63;
    const int wr=w/WN, wc=w%WN;
    const int lr=lane&15, lg=lane>>4;
    const int z=blockIdx.z, zb=z/zH, zh=z%zH;
    const long row0 = SWAP ? (long)blockIdx.x*BM : (long)blockIdx.y*BM;
    const long col0 = SWAP ? (long)blockIdx.y*BN : (long)blockIdx.x*BN;

    const unsigned short* Ab = A + zb*aSb + zh*aSh;
    const unsigned short* Bb = B + zb*bSb + zh*bSh;

    const int lr8 = lane>>3;          // row within 8-row chunk
    const int lc8 = (lane&7)<<3;      // col elem (16B slot)

    f32x4 acc[FM][FN];
    f32x4 acc2[GEGLU?FM:1][GEGLU?FN:1];
    #pragma unroll
    for(int i=0;i<FM;i++)
        #pragma unroll
        for(int j=0;j<FN;j++){
            acc[i][j]=f32x4{0.f,0.f,0.f,0.f};
            if constexpr(GEGLU) acc2[i][j]=f32x4{0.f,0.f,0.f,0.f};
        }

    const int NT=K/BK;
    for(int kt=0;kt<NT;kt++){
        const int kb=kt*BK;
        #pragma unroll
        for(int cc=0;cc<CA/4;cc++){
            const int c=cc*4+w;
            gl16(Ab + (row0 + c*8 + lr8)*(long)lda + kb + lc8, (char*)As + c*1024);
        }
        #pragma unroll
        for(int cc=0;cc<CB/4;cc++){
            const int c=cc*4+w;
            gl16(Bb + (col0 + c*8 + lr8)*(long)ldb + kb + lc8, (char*)Bs + c*1024);
        }
        if constexpr(GEGLU){
            #pragma unroll
            for(int cc=0;cc<CB/4;cc++){
                const int c=cc*4+w;
                gl16(B2 + (col0 + c*8 + lr8)*(long)ldb + kb + lc8,
                     (char*)Bs + (CB + c)*1024);
            }
        }
        __syncthreads();
        const unsigned short* Arp = As + (wr*WTM+lr)*BK + lg*8;
        const unsigned short* Brp = Bs + (wc*WTN+lr)*BK + lg*8;
        #pragma unroll
        for(int kk=0;kk<2;kk++){
            s16x8 af[FM], bfv[FN], bf2[GEGLU?FN:1];
            #pragma unroll
            for(int i=0;i<FM;i++) af[i] = *(const s16x8*)(Arp + i*16*BK + kk*32);
            #pragma unroll
            for(int j=0;j<FN;j++) bfv[j]= *(const s16x8*)(Brp + j*16*BK + kk*32);
            if constexpr(GEGLU){
                #pragma unroll
                for(int j=0;j<FN;j++) bf2[j]=*(const s16x8*)(Brp + BN*BK + j*16*BK + kk*32);
            }
            #pragma unroll
            for(int i=0;i<FM;i++)
                #pragma unroll
                for(int j=0;j<FN;j++){
                    acc[i][j]=__builtin_amdgcn_mfma_f32_16x16x32_bf16(af[i],bfv[j],acc[i][j],0,0,0);
                    if constexpr(GEGLU)
                        acc2[i][j]=__builtin_amdgcn_mfma_f32_16x16x32_bf16(af[i],bf2[j],acc2[i][j],0,0,0);
                }
        }
        __syncthreads();
    }
    #pragma unroll
    for(int i=0;i<FM;i++){
        #pragma unroll
        for(int j=0;j<FN;j++){
            #pragma unroll
            for(int r=0;r<4;r++){
                const long grow = row0 + wr*WTM + i*16 + lg*4 + r;
                const long gcol = col0 + wc*WTN + j*16 + lr;
                if constexpr(GEGLU){
                    float g  = acc[i][j][r]  + bias[gcol];
                    float vl = acc2[i][j][r] + bias[gcol+4096];
                    float ge = 0.5f*g*(1.f+erff(g*0.70710678118654752f));
                    ((unsigned short*)Cp)[grow*ldc+gcol] = f2bf(ge*vl);
                } else {
                    float vv=acc[i][j][r];
                    if constexpr(SCL)  vv*=ATT_SCALE;
                    if constexpr(BIAS) vv+=bias[gcol];
                    if constexpr(RES)  vv+=res[grow*ldc+gcol];
                    const long cidx = zb*cSb + zh*cSh + grow*ldc + gcol;
                    if constexpr(OBF16) ((unsigned short*)Cp)[cidx]=f2bf(vv);
                    else                ((float*)Cp)[cidx]=vv;
                }
            }
        }
    }
}

// ---------------------------------------------------------------------------
// Tiled 64x64 transpose: in (rows,cols) -> out (cols,rows) bf16.
// IN32: input f32 (converted to bf16). z batching: zb=z/zH, zh=z%zH.
// ---------------------------------------------------------------------------
template<bool IN32>
__global__ __launch_bounds__(256) void tr_k(const void* __restrict__ in,
    unsigned short* __restrict__ out, int ldin, int ldout,
    long inZb, long inZh, long outZb, long outZh, int zH)
{
    __shared__ unsigned short tl[64][68];
    const int t=threadIdx.x;
    const int z=blockIdx.z, zb=z/zH, zh=z%zH;
    const long ib=(long)blockIdx.x*64*ldin + (long)blockIdx.y*64 + zb*inZb + zh*inZh;
    const long ob=(long)blockIdx.y*64*ldout + (long)blockIdx.x*64 + zb*outZb + zh*outZh;
    const int r0=t>>4, c0=(t&15)*4;
    #pragma unroll
    for(int p=0;p<4;p++){
        const int rr=r0+p*16;
        if constexpr(IN32){
            f32x4 v=*(const f32x4*)((const float*)in + ib + (long)rr*ldin + c0);
            #pragma unroll
            for(int i=0;i<4;i++) tl[c0+i][rr]=f2bf(v[i]);
        } else {
            s16x4 v=*(const s16x4*)((const unsigned short*)in + ib + (long)rr*ldin + c0);
            #pragma unroll
            for(int i=0;i<4;i++) tl[c0+i][rr]=(unsigned short)v[i];
        }
    }
    __syncthreads();
    #pragma unroll
    for(int p=0;p<4;p++){
        const int rr=r0+p*16;
        s16x4 o4;
        #pragma unroll
        for(int i=0;i<4;i++) o4[i]=(short)tl[rr][c0+i];
        *(s16x4*)(out + ob + (long)rr*ldout + c0)=o4;
    }
}

// ---------------------------------------------------------------------------
// LayerNorm over D=1024 (one block per row). GATHER: src row = tok_emb[tok[row]].
// ---------------------------------------------------------------------------
template<bool GATHER, bool OBF16>
__global__ __launch_bounds__(256) void ln_k(const float* __restrict__ in,
    const float* __restrict__ w, const float* __restrict__ b,
    void* __restrict__ out, const int* __restrict__ tok)
{
    const int row = blockIdx.x, t = threadIdx.x;
    const float* src;
    if constexpr (GATHER) src = in + (long)tok[row]*1024;
    else                  src = in + (long)row*1024;
    const int c = t*4;
    f32x4 xv = *(const f32x4*)(src + c);
    float s  = xv[0]+xv[1]+xv[2]+xv[3];
    float qq = xv[0]*xv[0]+xv[1]*xv[1]+xv[2]*xv[2]+xv[3]*xv[3];
    #pragma unroll
    for(int m=32;m;m>>=1){ s += __shfl_xor(s,m); qq += __shfl_xor(qq,m); }
    __shared__ float rs_[4], rq_[4];
    if((t&63)==0){ rs_[t>>6]=s; rq_[t>>6]=qq; }
    __syncthreads();
    s  = rs_[0]+rs_[1]+rs_[2]+rs_[3];
    qq = rq_[0]+rq_[1]+rq_[2]+rq_[3];
    const float mu = s*(1.f/1024.f);
    const float rstd = rsqrtf(qq*(1.f/1024.f)-mu*mu + 1e-5f);
    f32x4 wv = *(const f32x4*)(w+c), bv = *(const f32x4*)(b+c);
    if constexpr (OBF16){
        s16x4 ov;
        #pragma unroll
        for(int i=0;i<4;i++) ov[i]=(short)f2bf((xv[i]-mu)*rstd*wv[i]+bv[i]);
        *(s16x4*)((unsigned short*)out + (long)row*1024 + c) = ov;
    } else {
        f32x4 ov;
        #pragma unroll
        for(int i=0;i<4;i++) ov[i]=(xv[i]-mu)*rstd*wv[i]+bv[i];
        *(f32x4*)((float*)out + (long)row*1024 + c) = ov;
    }
}

// ---------------------------------------------------------------------------
// In-place row softmax on bf16 scores; row = 2048 elems, one block per row.
// ---------------------------------------------------------------------------
__global__ __launch_bounds__(256) void softmax_k(unsigned short* __restrict__ p)
{
    const long row = blockIdx.x;
    unsigned short* rp = p + row*2048;
    const int t = threadIdx.x;
    s16x8 sv = *(s16x8*)(rp + t*8);
    float v[8]; float m=-1e30f;
    #pragma unroll
    for(int i=0;i<8;i++){ v[i]=bf2f((unsigned short)sv[i]); m=fmaxf(m,v[i]); }
    #pragma unroll
    for(int mm=32;mm;mm>>=1) m = fmaxf(m, __shfl_xor(m,mm));
    __shared__ float rm[4], rsum[4];
    if((t&63)==0) rm[t>>6]=m;
    __syncthreads();
    m = fmaxf(fmaxf(rm[0],rm[1]),fmaxf(rm[2],rm[3]));
    float s=0.f;
    #pragma unroll
    for(int i=0;i<8;i++){ v[i]=__expf(v[i]-m); s+=v[i]; }
    #pragma unroll
    for(int mm=32;mm;mm>>=1) s += __shfl_xor(s,mm);
    if((t&63)==0) rsum[t>>6]=s;
    __syncthreads();
    s = rsum[0]+rsum[1]+rsum[2]+rsum[3];
    const float inv = 1.f/s;
    s16x8 ov;
    #pragma unroll
    for(int i=0;i<8;i++) ov[i]=(short)f2bf(v[i]*inv);
    *(s16x8*)(rp + t*8) = ov;
}

// ---------------------------------------------------------------------------
// Slow fallback GEMM (round-0 structure) — used only for tier-C logits.
// ---------------------------------------------------------------------------
template<int BM,int BN,int WN,bool BF32,bool BTRANS,bool BIAS,bool RES,bool OBF16,bool SCL>
__global__ __launch_bounds__(256) void gemm_k(
    const unsigned short* __restrict__ A,
    const void* __restrict__ Bp,
    const float* __restrict__ bias,
    const float* __restrict__ res,
    void* __restrict__ Cp,
    int M,int N,int K,int lda,int ldb,int ldc,
    long aSb,long aSh,long bSb,long bSh,long cSb,long cSh,int zH)
{
    constexpr int BK=64, PAD=24, LDS_=BK+PAD;
    constexpr int WM = 4/WN;
    constexpr int WTM = BM/WM, WTN = BN/WN;
    constexpr int FM = WTM/16, FN = WTN/16;
    __shared__ unsigned short As[BM*LDS_];
    __shared__ unsigned short Bs[BN*LDS_];

    const int t = threadIdx.x;
    const int w = t>>6, lane = t&63;
    const int wr = w / WN, wc = w % WN;
    const int lr = lane & 15, lg = lane >> 4;

    const int z = blockIdx.z;
    const int zb = z / zH, zh = z % zH;
    const long row0 = (long)blockIdx.y*BM;
    const long col0 = (long)blockIdx.x*BN;

    const unsigned short* Ab = A + zb*aSb + zh*aSh;

    f32x4 acc[FM][FN];
    #pragma unroll
    for(int i=0;i<FM;i++)
        #pragma unroll
        for(int j=0;j<FN;j++) acc[i][j] = f32x4{0.f,0.f,0.f,0.f};

    const int NT = K/BK;
    for(int kt=0; kt<NT; ++kt){
        const int kb = kt*BK;
        {
            constexpr int PASS = BM*BK/(256*4);
            #pragma unroll
            for(int p=0;p<PASS;p++){
                int idx = (p*256+t)*4;
                int r = idx/BK, c = idx%BK;
                *(s16x4*)&As[r*LDS_+c] = *(const s16x4*)(Ab + (row0+r)*lda + kb + c);
            }
        }
        {
            constexpr int TPB = 256/BN;
            constexpr int KC  = BK/TPB;
            const int n = t % BN, k0 = (t/BN)*KC;
            #pragma unroll
            for(int j0=0;j0<KC;j0+=8){
                s16x8 pk;
                #pragma unroll
                for(int i=0;i<8;i++){
                    const long gk = (long)kb + k0 + j0 + i;
                    const float* Bb = (const float*)Bp + zb*bSb + zh*bSh;
                    pk[i] = (short)f2bf(Bb[gk*ldb + col0 + n]);
                }
                *(s16x8*)&Bs[n*LDS_ + k0 + j0] = pk;
            }
        }
        __syncthreads();
        const unsigned short* Ar = &As[(wr*WTM + lr)*LDS_ + lg*8];
        const unsigned short* Br = &Bs[(wc*WTN + lr)*LDS_ + lg*8];
        #pragma unroll
        for(int kk=0;kk<BK/32;kk++){
            s16x8 af[FM], bfv[FN];
            #pragma unroll
            for(int i=0;i<FM;i++) af[i]  = *(const s16x8*)(Ar + i*16*LDS_ + kk*32);
            #pragma unroll
            for(int j=0;j<FN;j++) bfv[j] = *(const s16x8*)(Br + j*16*LDS_ + kk*32);
            #pragma unroll
            for(int i=0;i<FM;i++)
                #pragma unroll
                for(int j=0;j<FN;j++)
                    acc[i][j] = __builtin_amdgcn_mfma_f32_16x16x32_bf16(af[i],bfv[j],acc[i][j],0,0,0);
        }
        __syncthreads();
    }
    #pragma unroll
    for(int i=0;i<FM;i++){
        #pragma unroll
        for(int j=0;j<FN;j++){
            #pragma unroll
            for(int r=0;r<4;r++){
                long grow = row0 + wr*WTM + i*16 + lg*4 + r;
                long gcol = col0 + wc*WTN + j*16 + lr;
                float vv = acc[i][j][r];
                if constexpr (BIAS) vv += bias[gcol];
                if constexpr (RES)  vv += res[grow*ldc + gcol];
                long cidx = zb*cSb + zh*cSh + grow*ldc + gcol;
                if constexpr (OBF16) ((unsigned short*)Cp)[cidx] = f2bf(vv);
                else                 ((float*)Cp)[cidx] = vv;
            }
        }
    }
}

// ---------------------------------------------------------------------------
extern "C" void kernel_launch(void* const* d_in, const int* in_sizes, int n_in,
                              void* d_out, int out_size, void* d_ws, size_t ws_size,
                              hipStream_t stream)
{
    const int*   tokens  = (const int*)  d_in[0];
    const float* tok_emb = (const float*)d_in[1];
    const float* ln_e_w  = (const float*)d_in[2];
    const float* ln_e_b  = (const float*)d_in[3];
    const float* ln1_w   = (const float*)d_in[4];
    const float* ln1_b   = (const float*)d_in[5];
    const float* wq      = (const float*)d_in[6];
    const float* bq      = (const float*)d_in[7];
    const float* wk      = (const float*)d_in[8];
    const float* bk      = (const float*)d_in[9];
    const float* wv      = (const float*)d_in[10];
    const float* bv      = (const float*)d_in[11];
    const float* wo      = (const float*)d_in[12];
    const float* bo      = (const float*)d_in[13];
    const float* ln2_w   = (const float*)d_in[14];
    const float* ln2_b   = (const float*)d_in[15];
    const float* w1      = (const float*)d_in[16];
    const float* b1      = (const float*)d_in[17];
    const float* w2      = (const float*)d_in[18];
    const float* b2      = (const float*)d_in[19];
    const float* lnf_w   = (const float*)d_in[20];
    const float* lnf_b   = (const float*)d_in[21];
    const float* w_out   = (const float*)d_in[22];
    const float* b_out   = (const float*)d_in[23];

    const int D=1024;
    const long SD  = 2048L*1024;       // per-batch stride (elems)
    const long SS  = 2048L*2048;       // per-head score stride
    const long HSS = 16*SS;
    const long DD  = (long)D*D;

    unsigned short* scores = (unsigned short*)d_out;   // 256MB bf16 scratch

    unsigned short *wqT,*wkT,*wvT,*woT,*w1T,*w2T,*woutT=nullptr;
    float* x; unsigned short *h,*q,*k,*v,*vt,*o,*ff;
    bool fastLogits;
    if (ws_size >= 301989888ull){
        char* p=(char*)d_ws;
        wqT =(unsigned short*)(p);
        wkT =(unsigned short*)(p+8388608);
        wvT =(unsigned short*)(p+16777216);
        woT =(unsigned short*)(p+25165824);
        w1T =(unsigned short*)(p+33554432);
        w2T =(unsigned short*)(p+100663296);
        woutT=(unsigned short*)(p+134217728);
        x   =(float*)(p+201326592);
        h   =(unsigned short*)(p+218103808);
        q   =(unsigned short*)(p+226492416);
        k   =(unsigned short*)(p+234881024);
        v   =(unsigned short*)(p+243269632);
        vt  =(unsigned short*)(p+251658240);
        o   =(unsigned short*)(p+260046848);
        ff  =(unsigned short*)(p+268435456);
        fastLogits=true;
    } else {
        char* p=(char*)d_out;
        wqT =(unsigned short*)(p+268435456);
        wkT =(unsigned short*)(p+276824064);
        wvT =(unsigned short*)(p+285212672);
        woT =(unsigned short*)(p+293601280);
        w1T =(unsigned short*)(p+301989888);
        w2T =(unsigned short*)(p+369098752);
        x   =(float*)(p+402653184);
        q   =(unsigned short*)(p+419430400);
        k   =(unsigned short*)(p+427819008);
        v   =(unsigned short*)(p+436207616);
        vt  =(unsigned short*)(p+444596224);
        o   =(unsigned short*)(p+452984832);
        ff  =(unsigned short*)(p+461373440);
        h   =(unsigned short*)d_ws;
        fastLogits=false;
    }

    const dim3 blk(256,1,1);

    // ---- weight conversion + transpose (f32 (K,N) -> bf16 (N,K)) ----
    tr_k<true><<<dim3(16,16,4), blk,0,stream>>>(wq, wqT, 1024,1024, DD,0, DD,0, 1);
    tr_k<true><<<dim3(16,16,4), blk,0,stream>>>(wk, wkT, 1024,1024, DD,0, DD,0, 1);
    tr_k<true><<<dim3(16,16,4), blk,0,stream>>>(wv, wvT, 1024,1024, DD,0, DD,0, 1);
    tr_k<true><<<dim3(16,16,4), blk,0,stream>>>(wo, woT, 1024,1024, DD,0, DD,0, 1);
    tr_k<true><<<dim3(16,128,4),blk,0,stream>>>(w1, w1T, 8192,1024, 8388608L,0, 8388608L,0, 1);
    tr_k<true><<<dim3(64,16,4), blk,0,stream>>>(w2, w2T, 1024,4096, 4194304L,0, 4194304L,0, 1);
    if (fastLogits)
        tr_k<true><<<dim3(16,500,1),blk,0,stream>>>(w_out, woutT, 32000,1024, 0,0, 0,0, 1);

    // ---- embed + ln_e -> x (f32) ----
    ln_k<true,false><<<4096,blk,0,stream>>>(tok_emb, ln_e_w, ln_e_b, x, tokens);

    const dim3 g_d (8,32,1), g_qk(16,16,32), g_pv(1,16,32), g_ff1(64,32,1);

    for(int l=0;l<4;l++){
        ln_k<false,true><<<4096,blk,0,stream>>>(x, ln1_w+l*D, ln1_b+l*D, h, nullptr);
        gemm_bt<128,128,2,true,false,true,false,false,false><<<g_d,blk,0,stream>>>(
            h, wqT+l*DD, nullptr, bq+l*D, nullptr, q, 1024, 1024,1024,1024, 0,0,0,0,0,0, 1);
        gemm_bt<128,128,2,true,false,true,false,false,false><<<g_d,blk,0,stream>>>(
            h, wkT+l*DD, nullptr, bk+l*D, nullptr, k, 1024, 1024,1024,1024, 0,0,0,0,0,0, 1);
        gemm_bt<128,128,2,true,false,true,false,false,false><<<g_d,blk,0,stream>>>(
            h, wvT+l*DD, nullptr, bv+l*D, nullptr, v, 1024, 1024,1024,1024, 0,0,0,0,0,0, 1);
        // v (b,s,h,hd) -> vt (b,h,hd,s)
        tr_k<false><<<dim3(32,1,32),blk,0,stream>>>(v, vt, 1024,2048, SD,64, 2097152L,131072L, 16);
        // scores = scale * q @ k^T
        gemm_bt<128,128,2,false,false,true,true,false,false><<<g_qk,blk,0,stream>>>(
            q, k, nullptr, nullptr, nullptr, scores, 64, 1024,1024,2048,
            SD,64, SD,64, HSS,SS, 16);
        softmax_k<<<65536,blk,0,stream>>>(scores);
        // o = P @ V   (B = vt (hd, s))
        gemm_bt<128,64,1,false,false,true,false,false,false><<<g_pv,blk,0,stream>>>(
            scores, vt, nullptr, nullptr, nullptr, o, 2048, 2048,2048,1024,
            HSS,SS, 2097152L,131072L, SD,64, 16);
        // x += o @ wo + bo
        gemm_bt<128,128,2,true,true,false,false,false,false><<<g_d,blk,0,stream>>>(
            o, woT+l*DD, nullptr, bo+l*D, x, x, 1024, 1024,1024,1024, 0,0,0,0,0,0, 1);
        // FFN: fused GeGLU (gate cols 0..4095, val cols 4096..8191 of w1T rows)
        ln_k<false,true><<<4096,blk,0,stream>>>(x, ln2_w+l*D, ln2_b+l*D, h, nullptr);
        gemm_bt<128,64,1,true,false,true,false,false,true><<<g_ff1,blk,0,stream>>>(
            h, w1T+l*8388608L, w1T+l*8388608L+4194304L, b1+(long)l*8192, nullptr, ff,
            1024, 1024,1024,4096, 0,0,0,0,0,0, 1);
        // x += ff @ w2 + b2
        gemm_bt<128,128,2,true,true,false,false,false,false><<<g_d,blk,0,stream>>>(
            ff, w2T+l*4194304L, nullptr, b2+l*D, x, x, 4096, 4096,4096,1024, 0,0,0,0,0,0, 1);
    }

    ln_k<false,true><<<4096,blk,0,stream>>>(x, lnf_w, lnf_b, h, nullptr);

    if (fastLogits){
        // grid: x = row panel (fastest) so 32 consecutive blocks share one B col-panel
        gemm_bt<128,128,2,true,false,false,false,true,false><<<dim3(32,250,1),blk,0,stream>>>(
            h, woutT, nullptr, b_out, nullptr, (float*)d_out, 1024, 1024,1024,32000,
            0,0,0,0,0,0, 1);
    } else {
        gemm_k<128,128,2,true,false,true,false,false,false><<<dim3(250,32,1),blk,0,stream>>>(
            h, w_out, b_out, nullptr, (float*)d_out, 4096,32000,1024, 1024,32000,32000,
            0,0,0,0,0,0, 1);
    }
}

// Round 3
// 2872.837 us; speedup vs baseline: 1.7501x; 1.0835x over previous
//
#include <hip/hip_runtime.h>

typedef __attribute__((ext_vector_type(8))) short s16x8;
typedef __attribute__((ext_vector_type(4))) short s16x4;
typedef __attribute__((ext_vector_type(4))) float f32x4;

__device__ __forceinline__ unsigned short f2bf(float f){
    union{float f;unsigned u;}v; v.f=f;
    unsigned u=v.u;
    unsigned r=(u+0x7fffu+((u>>16)&1u))>>16;
    return (unsigned short)r;
}
__device__ __forceinline__ float bf2f(unsigned short s){
    union{unsigned u;float f;}v; v.u=((unsigned)s)<<16; return v.f;
}

__device__ __forceinline__ void gl16(const void* g, void* l){
    __builtin_amdgcn_global_load_lds(
        (const __attribute__((address_space(1))) void*)g,
        (__attribute__((address_space(3))) void*)l, 16, 0, 0);
}

#define ATT_SCALE 0.125f

// ===========================================================================
// 8-phase 256x256 GEMM (T2+T3+T4+T5): A (M,K) bf16 rm, B (N,K) bf16 rm.
// 512 threads = 8 waves (2M x 4N), BK=64, dbuf LDS 128KiB, counted vmcnt.
// grid: x = M-tiles (fast), y = N-tiles; nwg must be %8==0 (XCD swizzle).
// ===========================================================================
template<bool OBF16,bool BIAS>
__global__ __launch_bounds__(512,2) void gemm8_k(
    const unsigned short* __restrict__ A,
    const unsigned short* __restrict__ B,
    const float* __restrict__ bias,
    void* __restrict__ Cp,
    int K,int lda,int ldb,int ldc)
{
    __shared__ __align__(16) char lds[131072];   // [A s0|A s1|B s0|B s1] 32KB each
    const int t=threadIdx.x, w=t>>6, lane=t&63;
    const int wr=w>>2, wc=w&3;
    const int lr=lane&15, lg=lane>>4;

    // bijective XCD swizzle (nwg % 8 == 0 at all call sites)
    const int nwg = gridDim.x*gridDim.y;
    const int id  = blockIdx.y*gridDim.x + blockIdx.x;
    const int nid = (id&7)*(nwg>>3) + (id>>3);
    const long row0 = (long)(nid % gridDim.x)*256;
    const long col0 = (long)(nid / gridDim.x)*256;

    const int NT = K>>6;                          // NT >= 2 required

    // per-lane swizzled read offsets: phys = row*128 + (col ^ ((row&7)<<4))
    const int csw0 = (lg*16) ^ ((lr&7)<<4);       // kk=0 col-slot; kk=1 -> ^64
    const int aRow = (wr*64+lr)*128;
    const int bRow = (wc*32+lr)*128;

    // per-thread staging constants: linear LDS dest, inverse-swizzled source
    const int sro = t>>3;                              // row within 64-row round
    const int sce = (((t&7) ^ ((t>>3)&7))<<3);         // swizzled source col elem

#define STAGE(gp, ld_, lb) do{ \
    const unsigned short* _g=(gp); char* _l=(lb); \
    gl16(_g + (long)sro*(ld_) + sce, _l + t*16); \
    gl16(_g + (long)(sro+64)*(ld_) + sce, _l + 8192 + t*16); }while(0)

#define LDA8(m,kk) (*(const s16x8*)(Ab_ + aRow + ((m)&3)*2048 + ((m)>>2)*16384 + ((kk)? (csw0^64):csw0)))
#define LDB8(n,kk) (*(const s16x8*)(Bb_ + bRow + ((n)&1)*2048 + ((n)>>1)*16384 + ((kk)? (csw0^64):csw0)))

    f32x4 acc[8][4];
    #pragma unroll
    for(int m=0;m<8;m++)
        #pragma unroll
        for(int n=0;n<4;n++) acc[m][n]=f32x4{0.f,0.f,0.f,0.f};

    // ---- prologue: A-lo(0),B-lo(0),A-hi(0),B-hi(0),A-lo(1),B-lo(1) ----
    STAGE(A + row0*lda,        lda, lds);
    STAGE(B + col0*ldb,        ldb, lds+65536);
    STAGE(A + (row0+128)*lda,  lda, lds+16384);
    STAGE(B + (col0+128)*ldb,  ldb, lds+65536+16384);
    STAGE(A + row0*lda + 64,   lda, lds+32768);
    STAGE(B + col0*ldb + 64,   ldb, lds+65536+32768);
    asm volatile("s_waitcnt vmcnt(4)" ::: "memory");   // tile 0 fully landed
    __builtin_amdgcn_s_barrier();

    for(int tt=0; tt<NT; ++tt){
        char* Ab_ = lds + ((tt&1)<<15);
        char* Bb_ = lds + 65536 + ((tt&1)<<15);
        char* An  = lds + (((tt+1)&1)<<15);
        char* Bn  = lds + 65536 + (((tt+1)&1)<<15);
        const int k1=(tt+1)<<6, k2=(tt+2)<<6;
        s16x8 a[4][2], b01[2][2], b23[2][2];

        // ---- q0: m0-3 x n0-1 ----
        #pragma unroll
        for(int m=0;m<4;m++){ a[m][0]=LDA8(m,0); a[m][1]=LDA8(m,1); }
        #pragma unroll
        for(int n=0;n<2;n++){ b01[n][0]=LDB8(n,0); b01[n][1]=LDB8(n,1); }
        if(tt+1<NT) STAGE(A + (row0+128)*lda + k1, lda, An+16384);   // A-hi(t+1)
        __builtin_amdgcn_s_barrier();
        __builtin_amdgcn_s_setprio(1);
        #pragma unroll
        for(int kk=0;kk<2;kk++)
            #pragma unroll
            for(int m=0;m<4;m++)
                #pragma unroll
                for(int n=0;n<2;n++)
                    acc[m][n]=__builtin_amdgcn_mfma_f32_16x16x32_bf16(a[m][kk],b01[n][kk],acc[m][n],0,0,0);
        __builtin_amdgcn_s_setprio(0);
        __builtin_amdgcn_s_barrier();

        // ---- q1: m0-3 x n2-3 ----
        #pragma unroll
        for(int n=0;n<2;n++){ b23[n][0]=LDB8(n+2,0); b23[n][1]=LDB8(n+2,1); }
        if(tt+1<NT) STAGE(B + (col0+128)*ldb + k1, ldb, Bn+16384);   // B-hi(t+1)
        __builtin_amdgcn_s_barrier();
        __builtin_amdgcn_s_setprio(1);
        #pragma unroll
        for(int kk=0;kk<2;kk++)
            #pragma unroll
            for(int m=0;m<4;m++)
                #pragma unroll
                for(int n=0;n<2;n++)
                    acc[m][n+2]=__builtin_amdgcn_mfma_f32_16x16x32_bf16(a[m][kk],b23[n][kk],acc[m][n+2],0,0,0);
        __builtin_amdgcn_s_setprio(0);
        __builtin_amdgcn_s_barrier();

        // ---- q2: m4-7 x n0-1 ----
        #pragma unroll
        for(int m=0;m<4;m++){ a[m][0]=LDA8(m+4,0); a[m][1]=LDA8(m+4,1); }
        if(tt+2<NT) STAGE(A + row0*lda + k2, lda, Ab_);              // A-lo(t+2)
        __builtin_amdgcn_s_barrier();
        __builtin_amdgcn_s_setprio(1);
        #pragma unroll
        for(int kk=0;kk<2;kk++)
            #pragma unroll
            for(int m=0;m<4;m++)
                #pragma unroll
                for(int n=0;n<2;n++)
                    acc[m+4][n]=__builtin_amdgcn_mfma_f32_16x16x32_bf16(a[m][kk],b01[n][kk],acc[m+4][n],0,0,0);
        __builtin_amdgcn_s_setprio(0);
        __builtin_amdgcn_s_barrier();

        // ---- q3: m4-7 x n2-3 ----
        if(tt+2<NT) STAGE(B + col0*ldb + k2, ldb, Bb_);              // B-lo(t+2)
        __builtin_amdgcn_s_barrier();
        __builtin_amdgcn_s_setprio(1);
        #pragma unroll
        for(int kk=0;kk<2;kk++)
            #pragma unroll
            for(int m=0;m<4;m++)
                #pragma unroll
                for(int n=0;n<2;n++)
                    acc[m+4][n+2]=__builtin_amdgcn_mfma_f32_16x16x32_bf16(a[m][kk],b23[n][kk],acc[m+4][n+2],0,0,0);
        __builtin_amdgcn_s_setprio(0);
        if(tt+2<NT) asm volatile("s_waitcnt vmcnt(4)" ::: "memory"); // tile t+1 complete
        else        asm volatile("s_waitcnt vmcnt(0)" ::: "memory");
        __builtin_amdgcn_s_barrier();
    }

    // ---- epilogue ----
    #pragma unroll
    for(int m=0;m<8;m++){
        #pragma unroll
        for(int n=0;n<4;n++){
            #pragma unroll
            for(int rr=0;rr<4;rr++){
                const long grow = row0 + wr*64 + (m&3)*16 + (m>>2)*128 + lg*4 + rr;
                const long gcol = col0 + wc*32 + (n&1)*16 + (n>>1)*128 + lr;
                float vv = acc[m][n][rr];
                if constexpr(BIAS) vv += bias[gcol];
                if constexpr(OBF16) ((unsigned short*)Cp)[grow*(long)ldc+gcol]=f2bf(vv);
                else                ((float*)Cp)[grow*(long)ldc+gcol]=vv;
            }
        }
    }
#undef STAGE
#undef LDA8
#undef LDB8
}

// ---------------------------------------------------------------------------
// GeGLU on bf16 gv (4096 x 8192): ff = gelu(gate) * val, bf16 out.
// ---------------------------------------------------------------------------
__global__ __launch_bounds__(256) void gelu8_k(const unsigned short* __restrict__ gv,
                                               unsigned short* __restrict__ ff)
{
    const long total8 = (long)4096*4096/8;
    for(long i8=(long)blockIdx.x*256+threadIdx.x; i8<total8; i8+=(long)gridDim.x*256){
        const long idx=i8*8;
        const long r=idx>>12; const int c=(int)(idx&4095);
        s16x8 g8=*(const s16x8*)(gv + r*8192 + c);
        s16x8 v8=*(const s16x8*)(gv + r*8192 + 4096 + c);
        s16x8 o8;
        #pragma unroll
        for(int i=0;i<8;i++){
            float gg=bf2f((unsigned short)g8[i]);
            float vl=bf2f((unsigned short)v8[i]);
            float ge=0.5f*gg*(1.f+erff(gg*0.70710678118654752f));
            o8[i]=(short)f2bf(ge*vl);
        }
        *(s16x8*)(ff+idx)=o8;
    }
}

// ---------------------------------------------------------------------------
// Fast 2-phase GEMM (m97 structure), 128-tile family.
// ---------------------------------------------------------------------------
template<int BM,int BN,int WN,bool BIAS,bool RES,bool OBF16,bool SCL,bool SWAP,bool GEGLU>
__global__ __launch_bounds__(256) void gemm_bt(
    const unsigned short* __restrict__ A,
    const unsigned short* __restrict__ B,
    const unsigned short* __restrict__ B2,
    const float* __restrict__ bias,
    const float* __restrict__ res,
    void* __restrict__ Cp,
    int K,int lda,int ldb,int ldc,
    long aSb,long aSh,long bSb,long bSh,long cSb,long cSh,int zH)
{
    constexpr int BK=64;
    constexpr int WM=4/WN, WTM=BM/WM, WTN=BN/WN;
    constexpr int FM=WTM/16, FN=WTN/16;
    constexpr int CA=BM/8, CB=BN/8;
    __shared__ __align__(16) unsigned short As[BM*BK];
    __shared__ __align__(16) unsigned short Bs[BN*BK*(GEGLU?2:1)];

    const int t=threadIdx.x, w=t>>6, lane=t&63;
    const int wr=w/WN, wc=w%WN;
    const int lr=lane&15, lg=lane>>4;
    const int z=blockIdx.z, zb=z/zH, zh=z%zH;
    const long row0 = SWAP ? (long)blockIdx.x*BM : (long)blockIdx.y*BM;
    const long col0 = SWAP ? (long)blockIdx.y*BN : (long)blockIdx.x*BN;

    const unsigned short* Ab = A + zb*aSb + zh*aSh;
    const unsigned short* Bb = B + zb*bSb + zh*bSh;

    const int lr8 = lane>>3;
    const int lc8 = (lane&7)<<3;

    f32x4 acc[FM][FN];
    f32x4 acc2[GEGLU?FM:1][GEGLU?FN:1];
    #pragma unroll
    for(int i=0;i<FM;i++)
        #pragma unroll
        for(int j=0;j<FN;j++){
            acc[i][j]=f32x4{0.f,0.f,0.f,0.f};
            if constexpr(GEGLU) acc2[i][j]=f32x4{0.f,0.f,0.f,0.f};
        }

    const int NT=K/BK;
    for(int kt=0;kt<NT;kt++){
        const int kb=kt*BK;
        #pragma unroll
        for(int cc=0;cc<CA/4;cc++){
            const int c=cc*4+w;
            gl16(Ab + (row0 + c*8 + lr8)*(long)lda + kb + lc8, (char*)As + c*1024);
        }
        #pragma unroll
        for(int cc=0;cc<CB/4;cc++){
            const int c=cc*4+w;
            gl16(Bb + (col0 + c*8 + lr8)*(long)ldb + kb + lc8, (char*)Bs + c*1024);
        }
        if constexpr(GEGLU){
            #pragma unroll
            for(int cc=0;cc<CB/4;cc++){
                const int c=cc*4+w;
                gl16(B2 + (col0 + c*8 + lr8)*(long)ldb + kb + lc8,
                     (char*)Bs + (CB + c)*1024);
            }
        }
        __syncthreads();
        const unsigned short* Arp = As + (wr*WTM+lr)*BK + lg*8;
        const unsigned short* Brp = Bs + (wc*WTN+lr)*BK + lg*8;
        #pragma unroll
        for(int kk=0;kk<2;kk++){
            s16x8 af[FM], bfv[FN], bf2[GEGLU?FN:1];
            #pragma unroll
            for(int i=0;i<FM;i++) af[i] = *(const s16x8*)(Arp + i*16*BK + kk*32);
            #pragma unroll
            for(int j=0;j<FN;j++) bfv[j]= *(const s16x8*)(Brp + j*16*BK + kk*32);
            if constexpr(GEGLU){
                #pragma unroll
                for(int j=0;j<FN;j++) bf2[j]=*(const s16x8*)(Brp + BN*BK + j*16*BK + kk*32);
            }
            #pragma unroll
            for(int i=0;i<FM;i++)
                #pragma unroll
                for(int j=0;j<FN;j++){
                    acc[i][j]=__builtin_amdgcn_mfma_f32_16x16x32_bf16(af[i],bfv[j],acc[i][j],0,0,0);
                    if constexpr(GEGLU)
                        acc2[i][j]=__builtin_amdgcn_mfma_f32_16x16x32_bf16(af[i],bf2[j],acc2[i][j],0,0,0);
                }
        }
        __syncthreads();
    }
    #pragma unroll
    for(int i=0;i<FM;i++){
        #pragma unroll
        for(int j=0;j<FN;j++){
            #pragma unroll
            for(int r=0;r<4;r++){
                const long grow = row0 + wr*WTM + i*16 + lg*4 + r;
                const long gcol = col0 + wc*WTN + j*16 + lr;
                if constexpr(GEGLU){
                    float g  = acc[i][j][r]  + bias[gcol];
                    float vl = acc2[i][j][r] + bias[gcol+4096];
                    float ge = 0.5f*g*(1.f+erff(g*0.70710678118654752f));
                    ((unsigned short*)Cp)[grow*ldc+gcol] = f2bf(ge*vl);
                } else {
                    float vv=acc[i][j][r];
                    if constexpr(SCL)  vv*=ATT_SCALE;
                    if constexpr(BIAS) vv+=bias[gcol];
                    if constexpr(RES)  vv+=res[grow*ldc+gcol];
                    const long cidx = zb*cSb + zh*cSh + grow*ldc + gcol;
                    if constexpr(OBF16) ((unsigned short*)Cp)[cidx]=f2bf(vv);
                    else                ((float*)Cp)[cidx]=vv;
                }
            }
        }
    }
}

// ---------------------------------------------------------------------------
// Tiled 64x64 transpose: in (rows,cols) -> out (cols,rows) bf16.
// ---------------------------------------------------------------------------
template<bool IN32>
__global__ __launch_bounds__(256) void tr_k(const void* __restrict__ in,
    unsigned short* __restrict__ out, int ldin, int ldout,
    long inZb, long inZh, long outZb, long outZh, int zH)
{
    __shared__ unsigned short tl[64][68];
    const int t=threadIdx.x;
    const int z=blockIdx.z, zb=z/zH, zh=z%zH;
    const long ib=(long)blockIdx.x*64*ldin + (long)blockIdx.y*64 + zb*inZb + zh*inZh;
    const long ob=(long)blockIdx.y*64*ldout + (long)blockIdx.x*64 + zb*outZb + zh*outZh;
    const int r0=t>>4, c0=(t&15)*4;
    #pragma unroll
    for(int p=0;p<4;p++){
        const int rr=r0+p*16;
        if constexpr(IN32){
            f32x4 v=*(const f32x4*)((const float*)in + ib + (long)rr*ldin + c0);
            #pragma unroll
            for(int i=0;i<4;i++) tl[c0+i][rr]=f2bf(v[i]);
        } else {
            s16x4 v=*(const s16x4*)((const unsigned short*)in + ib + (long)rr*ldin + c0);
            #pragma unroll
            for(int i=0;i<4;i++) tl[c0+i][rr]=(unsigned short)v[i];
        }
    }
    __syncthreads();
    #pragma unroll
    for(int p=0;p<4;p++){
        const int rr=r0+p*16;
        s16x4 o4;
        #pragma unroll
        for(int i=0;i<4;i++) o4[i]=(short)tl[rr][c0+i];
        *(s16x4*)(out + ob + (long)rr*ldout + c0)=o4;
    }
}

// ---------------------------------------------------------------------------
template<bool GATHER, bool OBF16>
__global__ __launch_bounds__(256) void ln_k(const float* __restrict__ in,
    const float* __restrict__ w, const float* __restrict__ b,
    void* __restrict__ out, const int* __restrict__ tok)
{
    const int row = blockIdx.x, t = threadIdx.x;
    const float* src;
    if constexpr (GATHER) src = in + (long)tok[row]*1024;
    else                  src = in + (long)row*1024;
    const int c = t*4;
    f32x4 xv = *(const f32x4*)(src + c);
    float s  = xv[0]+xv[1]+xv[2]+xv[3];
    float qq = xv[0]*xv[0]+xv[1]*xv[1]+xv[2]*xv[2]+xv[3]*xv[3];
    #pragma unroll
    for(int m=32;m;m>>=1){ s += __shfl_xor(s,m); qq += __shfl_xor(qq,m); }
    __shared__ float rs_[4], rq_[4];
    if((t&63)==0){ rs_[t>>6]=s; rq_[t>>6]=qq; }
    __syncthreads();
    s  = rs_[0]+rs_[1]+rs_[2]+rs_[3];
    qq = rq_[0]+rq_[1]+rq_[2]+rq_[3];
    const float mu = s*(1.f/1024.f);
    const float rstd = rsqrtf(qq*(1.f/1024.f)-mu*mu + 1e-5f);
    f32x4 wv = *(const f32x4*)(w+c), bv = *(const f32x4*)(b+c);
    if constexpr (OBF16){
        s16x4 ov;
        #pragma unroll
        for(int i=0;i<4;i++) ov[i]=(short)f2bf((xv[i]-mu)*rstd*wv[i]+bv[i]);
        *(s16x4*)((unsigned short*)out + (long)row*1024 + c) = ov;
    } else {
        f32x4 ov;
        #pragma unroll
        for(int i=0;i<4;i++) ov[i]=(xv[i]-mu)*rstd*wv[i]+bv[i];
        *(f32x4*)((float*)out + (long)row*1024 + c) = ov;
    }
}

// ---------------------------------------------------------------------------
__global__ __launch_bounds__(256) void softmax_k(unsigned short* __restrict__ p)
{
    const long row = blockIdx.x;
    unsigned short* rp = p + row*2048;
    const int t = threadIdx.x;
    s16x8 sv = *(s16x8*)(rp + t*8);
    float v[8]; float m=-1e30f;
    #pragma unroll
    for(int i=0;i<8;i++){ v[i]=bf2f((unsigned short)sv[i]); m=fmaxf(m,v[i]); }
    #pragma unroll
    for(int mm=32;mm;mm>>=1) m = fmaxf(m, __shfl_xor(m,mm));
    __shared__ float rm[4], rsum[4];
    if((t&63)==0) rm[t>>6]=m;
    __syncthreads();
    m = fmaxf(fmaxf(rm[0],rm[1]),fmaxf(rm[2],rm[3]));
    float s=0.f;
    #pragma unroll
    for(int i=0;i<8;i++){ v[i]=__expf(v[i]-m); s+=v[i]; }
    #pragma unroll
    for(int mm=32;mm;mm>>=1) s += __shfl_xor(s,mm);
    if((t&63)==0) rsum[t>>6]=s;
    __syncthreads();
    s = rsum[0]+rsum[1]+rsum[2]+rsum[3];
    const float inv = 1.f/s;
    s16x8 ov;
    #pragma unroll
    for(int i=0;i<8;i++) ov[i]=(short)f2bf(v[i]*inv);
    *(s16x8*)(rp + t*8) = ov;
}

// ---------------------------------------------------------------------------
// Slow fallback GEMM (f32 B transposed in-kernel) — tier-C logits only.
// ---------------------------------------------------------------------------
template<int BM,int BN,int WN,bool BF32,bool BTRANS,bool BIAS,bool RES,bool OBF16,bool SCL>
__global__ __launch_bounds__(256) void gemm_k(
    const unsigned short* __restrict__ A,
    const void* __restrict__ Bp,
    const float* __restrict__ bias,
    const float* __restrict__ res,
    void* __restrict__ Cp,
    int M,int N,int K,int lda,int ldb,int ldc,
    long aSb,long aSh,long bSb,long bSh,long cSb,long cSh,int zH)
{
    constexpr int BK=64, PAD=24, LDS_=BK+PAD;
    constexpr int WM = 4/WN;
    constexpr int WTM = BM/WM, WTN = BN/WN;
    constexpr int FM = WTM/16, FN = WTN/16;
    __shared__ unsigned short As[BM*LDS_];
    __shared__ unsigned short Bs[BN*LDS_];

    const int t = threadIdx.x;
    const int w = t>>6, lane = t&63;
    const int wr = w / WN, wc = w % WN;
    const int lr = lane & 15, lg = lane >> 4;

    const int z = blockIdx.z;
    const int zb = z / zH, zh = z % zH;
    const long row0 = (long)blockIdx.y*BM;
    const long col0 = (long)blockIdx.x*BN;

    const unsigned short* Ab = A + zb*aSb + zh*aSh;

    f32x4 acc[FM][FN];
    #pragma unroll
    for(int i=0;i<FM;i++)
        #pragma unroll
        for(int j=0;j<FN;j++) acc[i][j] = f32x4{0.f,0.f,0.f,0.f};

    const int NT = K/BK;
    for(int kt=0; kt<NT; ++kt){
        const int kb = kt*BK;
        {
            constexpr int PASS = BM*BK/(256*4);
            #pragma unroll
            for(int p=0;p<PASS;p++){
                int idx = (p*256+t)*4;
                int r = idx/BK, c = idx%BK;
                *(s16x4*)&As[r*LDS_+c] = *(const s16x4*)(Ab + (row0+r)*lda + kb + c);
            }
        }
        {
            constexpr int TPB = 256/BN;
            constexpr int KC  = BK/TPB;
            const int n = t % BN, k0 = (t/BN)*KC;
            #pragma unroll
            for(int j0=0;j0<KC;j0+=8){
                s16x8 pk;
                #pragma unroll
                for(int i=0;i<8;i++){
                    const long gk = (long)kb + k0 + j0 + i;
                    const float* Bb = (const float*)Bp + zb*bSb + zh*bSh;
                    pk[i] = (short)f2bf(Bb[gk*ldb + col0 + n]);
                }
                *(s16x8*)&Bs[n*LDS_ + k0 + j0] = pk;
            }
        }
        __syncthreads();
        const unsigned short* Ar = &As[(wr*WTM + lr)*LDS_ + lg*8];
        const unsigned short* Br = &Bs[(wc*WTN + lr)*LDS_ + lg*8];
        #pragma unroll
        for(int kk=0;kk<BK/32;kk++){
            s16x8 af[FM], bfv[FN];
            #pragma unroll
            for(int i=0;i<FM;i++) af[i]  = *(const s16x8*)(Ar + i*16*LDS_ + kk*32);
            #pragma unroll
            for(int j=0;j<FN;j++) bfv[j] = *(const s16x8*)(Br + j*16*LDS_ + kk*32);
            #pragma unroll
            for(int i=0;i<FM;i++)
                #pragma unroll
                for(int j=0;j<FN;j++)
                    acc[i][j] = __builtin_amdgcn_mfma_f32_16x16x32_bf16(af[i],bfv[j],acc[i][j],0,0,0);
        }
        __syncthreads();
    }
    #pragma unroll
    for(int i=0;i<FM;i++){
        #pragma unroll
        for(int j=0;j<FN;j++){
            #pragma unroll
            for(int r=0;r<4;r++){
                long grow = row0 + wr*WTM + i*16 + lg*4 + r;
                long gcol = col0 + wc*WTN + j*16 + lr;
                float vv = acc[i][j][r];
                if constexpr (BIAS) vv += bias[gcol];
                if constexpr (RES)  vv += res[grow*ldc + gcol];
                long cidx = zb*cSb + zh*cSh + grow*ldc + gcol;
                if constexpr (OBF16) ((unsigned short*)Cp)[cidx] = f2bf(vv);
                else                 ((float*)Cp)[cidx] = vv;
            }
        }
    }
}

// ---------------------------------------------------------------------------
extern "C" void kernel_launch(void* const* d_in, const int* in_sizes, int n_in,
                              void* d_out, int out_size, void* d_ws, size_t ws_size,
                              hipStream_t stream)
{
    const int*   tokens  = (const int*)  d_in[0];
    const float* tok_emb = (const float*)d_in[1];
    const float* ln_e_w  = (const float*)d_in[2];
    const float* ln_e_b  = (const float*)d_in[3];
    const float* ln1_w   = (const float*)d_in[4];
    const float* ln1_b   = (const float*)d_in[5];
    const float* wq      = (const float*)d_in[6];
    const float* bq      = (const float*)d_in[7];
    const float* wk      = (const float*)d_in[8];
    const float* bk      = (const float*)d_in[9];
    const float* wv      = (const float*)d_in[10];
    const float* bv      = (const float*)d_in[11];
    const float* wo      = (const float*)d_in[12];
    const float* bo      = (const float*)d_in[13];
    const float* ln2_w   = (const float*)d_in[14];
    const float* ln2_b   = (const float*)d_in[15];
    const float* w1      = (const float*)d_in[16];
    const float* b1      = (const float*)d_in[17];
    const float* w2      = (const float*)d_in[18];
    const float* b2      = (const float*)d_in[19];
    const float* lnf_w   = (const float*)d_in[20];
    const float* lnf_b   = (const float*)d_in[21];
    const float* w_out   = (const float*)d_in[22];
    const float* b_out   = (const float*)d_in[23];

    const int D=1024;
    const long SD  = 2048L*1024;
    const long SS  = 2048L*2048;
    const long HSS = 16*SS;
    const long DD  = (long)D*D;

    unsigned short* scores = (unsigned short*)d_out;                      // 256MB
    unsigned short* gv8 = (unsigned short*)((char*)d_out + 268435456ull); // 64MB (fast tier)

    unsigned short *wqT,*wkT,*wvT,*woT,*w1T,*w2T,*woutT=nullptr;
    float* x; unsigned short *h,*q,*k,*v,*vt,*o,*ff;
    bool fastTier;
    if (ws_size >= 301989888ull){
        char* p=(char*)d_ws;
        wqT =(unsigned short*)(p);
        wkT =(unsigned short*)(p+8388608);
        wvT =(unsigned short*)(p+16777216);
        woT =(unsigned short*)(p+25165824);
        w1T =(unsigned short*)(p+33554432);
        w2T =(unsigned short*)(p+100663296);
        woutT=(unsigned short*)(p+134217728);
        x   =(float*)(p+201326592);
        h   =(unsigned short*)(p+218103808);
        q   =(unsigned short*)(p+226492416);
        k   =(unsigned short*)(p+234881024);
        v   =(unsigned short*)(p+243269632);
        vt  =(unsigned short*)(p+251658240);
        o   =(unsigned short*)(p+260046848);
        ff  =(unsigned short*)(p+268435456);
        fastTier=true;
    } else {
        char* p=(char*)d_out;
        wqT =(unsigned short*)(p+268435456);
        wkT =(unsigned short*)(p+276824064);
        wvT =(unsigned short*)(p+285212672);
        woT =(unsigned short*)(p+293601280);
        w1T =(unsigned short*)(p+301989888);
        w2T =(unsigned short*)(p+369098752);
        x   =(float*)(p+402653184);
        q   =(unsigned short*)(p+419430400);
        k   =(unsigned short*)(p+427819008);
        v   =(unsigned short*)(p+436207616);
        vt  =(unsigned short*)(p+444596224);
        o   =(unsigned short*)(p+452984832);
        ff  =(unsigned short*)(p+461373440);
        h   =(unsigned short*)d_ws;
        fastTier=false;
    }

    const dim3 blk(256,1,1), blk8(512,1,1);

    tr_k<true><<<dim3(16,16,4), blk,0,stream>>>(wq, wqT, 1024,1024, DD,0, DD,0, 1);
    tr_k<true><<<dim3(16,16,4), blk,0,stream>>>(wk, wkT, 1024,1024, DD,0, DD,0, 1);
    tr_k<true><<<dim3(16,16,4), blk,0,stream>>>(wv, wvT, 1024,1024, DD,0, DD,0, 1);
    tr_k<true><<<dim3(16,16,4), blk,0,stream>>>(wo, woT, 1024,1024, DD,0, DD,0, 1);
    tr_k<true><<<dim3(16,128,4),blk,0,stream>>>(w1, w1T, 8192,1024, 8388608L,0, 8388608L,0, 1);
    tr_k<true><<<dim3(64,16,4), blk,0,stream>>>(w2, w2T, 1024,4096, 4194304L,0, 4194304L,0, 1);
    if (fastTier)
        tr_k<true><<<dim3(16,500,1),blk,0,stream>>>(w_out, woutT, 32000,1024, 0,0, 0,0, 1);

    ln_k<true,false><<<4096,blk,0,stream>>>(tok_emb, ln_e_w, ln_e_b, x, tokens);

    const dim3 g_d (8,32,1), g_qk(16,16,32), g_pv(1,16,32), g_ff1f(64,32,1);

    for(int l=0;l<4;l++){
        ln_k<false,true><<<4096,blk,0,stream>>>(x, ln1_w+l*D, ln1_b+l*D, h, nullptr);
        gemm_bt<128,128,2,true,false,true,false,false,false><<<g_d,blk,0,stream>>>(
            h, wqT+l*DD, nullptr, bq+l*D, nullptr, q, 1024, 1024,1024,1024, 0,0,0,0,0,0, 1);
        gemm_bt<128,128,2,true,false,true,false,false,false><<<g_d,blk,0,stream>>>(
            h, wkT+l*DD, nullptr, bk+l*D, nullptr, k, 1024, 1024,1024,1024, 0,0,0,0,0,0, 1);
        gemm_bt<128,128,2,true,false,true,false,false,false><<<g_d,blk,0,stream>>>(
            h, wvT+l*DD, nullptr, bv+l*D, nullptr, v, 1024, 1024,1024,1024, 0,0,0,0,0,0, 1);
        tr_k<false><<<dim3(32,1,32),blk,0,stream>>>(v, vt, 1024,2048, SD,64, 2097152L,131072L, 16);
        gemm_bt<128,128,2,false,false,true,true,false,false><<<g_qk,blk,0,stream>>>(
            q, k, nullptr, nullptr, nullptr, scores, 64, 1024,1024,2048,
            SD,64, SD,64, HSS,SS, 16);
        softmax_k<<<65536,blk,0,stream>>>(scores);
        gemm_bt<128,64,1,false,false,true,false,false,false><<<g_pv,blk,0,stream>>>(
            scores, vt, nullptr, nullptr, nullptr, o, 2048, 2048,2048,1024,
            HSS,SS, 2097152L,131072L, SD,64, 16);
        gemm_bt<128,128,2,true,true,false,false,false,false><<<g_d,blk,0,stream>>>(
            o, woT+l*DD, nullptr, bo+l*D, x, x, 1024, 1024,1024,1024, 0,0,0,0,0,0, 1);
        ln_k<false,true><<<4096,blk,0,stream>>>(x, ln2_w+l*D, ln2_b+l*D, h, nullptr);
        if (fastTier){
            // FF1 via 8-phase 256^2 (bf16 out, +bias), then GeGLU elementwise
            gemm8_k<true,true><<<dim3(16,32,1),blk8,0,stream>>>(
                h, w1T+l*8388608L, b1+(long)l*8192, gv8, 1024, 1024,1024,8192);
            gelu8_k<<<2048,blk,0,stream>>>(gv8, ff);
        } else {
            gemm_bt<128,64,1,true,false,true,false,false,true><<<g_ff1f,blk,0,stream>>>(
                h, w1T+l*8388608L, w1T+l*8388608L+4194304L, b1+(long)l*8192, nullptr, ff,
                1024, 1024,1024,4096, 0,0,0,0,0,0, 1);
        }
        gemm_bt<128,128,2,true,true,false,false,false,false><<<g_d,blk,0,stream>>>(
            ff, w2T+l*4194304L, nullptr, b2+l*D, x, x, 4096, 4096,4096,1024, 0,0,0,0,0,0, 1);
    }

    ln_k<false,true><<<4096,blk,0,stream>>>(x, lnf_w, lnf_b, h, nullptr);

    if (fastTier){
        gemm8_k<false,true><<<dim3(16,125,1),blk8,0,stream>>>(
            h, woutT, b_out, (float*)d_out, 1024, 1024,1024,32000);
    } else {
        gemm_k<128,128,2,true,false,true,false,false,false><<<dim3(250,32,1),blk,0,stream>>>(
            h, w_out, b_out, nullptr, (float*)d_out, 4096,32000,1024, 1024,32000,32000,
            0,0,0,0,0,0, 1);
    }
}

// Round 5
// 2175.638 us; speedup vs baseline: 2.3109x; 1.3205x over previous
//
#include <hip/hip_runtime.h>

typedef __attribute__((ext_vector_type(8))) short s16x8;
typedef __attribute__((ext_vector_type(4))) short s16x4;
typedef __attribute__((ext_vector_type(4))) float f32x4;

__device__ __forceinline__ unsigned short f2bf(float f){
    union{float f;unsigned u;}v; v.f=f;
    unsigned u=v.u;
    unsigned r=(u+0x7fffu+((u>>16)&1u))>>16;
    return (unsigned short)r;
}
__device__ __forceinline__ float bf2f(unsigned short s){
    union{unsigned u;float f;}v; v.u=((unsigned)s)<<16; return v.f;
}
__device__ __forceinline__ unsigned pk2t(float a, float b){   // truncating bf16 pack
    return (__float_as_uint(a)>>16) | (__float_as_uint(b) & 0xffff0000u);
}
__device__ __forceinline__ unsigned pk2r(float a, float b){   // rounding bf16 pack
    return (unsigned)f2bf(a) | ((unsigned)f2bf(b)<<16);
}
__device__ __forceinline__ f32x4 fmax4(f32x4 a, f32x4 b){
    f32x4 r; r[0]=fmaxf(a[0],b[0]); r[1]=fmaxf(a[1],b[1]);
    r[2]=fmaxf(a[2],b[2]); r[3]=fmaxf(a[3],b[3]); return r;
}

__device__ __forceinline__ void gl16(const void* g, void* l){
    __builtin_amdgcn_global_load_lds(
        (const __attribute__((address_space(1))) void*)g,
        (__attribute__((address_space(3))) void*)l, 16, 0, 0);
}

#define ATT_SCALE 0.125f

// ===========================================================================
// Flash attention: qkv (B*S, 3072) bf16 [q|k|v], vt (B,H,64,2048) bf16.
// 4 waves/wg, 128 q-rows/wg (32/wave), KVBLK=64, online softmax, o bf16.
// ===========================================================================
__global__ __launch_bounds__(256) void flash_k(
    const unsigned short* __restrict__ qkv,
    const unsigned short* __restrict__ vt,
    unsigned short* __restrict__ o)
{
    __shared__ __align__(16) unsigned short Pl[4][2048];   // per-wave P 32x64
    const int t=threadIdx.x, w=t>>6, lane=t&63;
    const int lr=lane&15, lg=lane>>4;
    const int zb=blockIdx.y>>4, zh=blockIdx.y&15;
    const long sr0 = (long)zb*2048 + blockIdx.x*128 + w*32;
    const unsigned short* qb    = qkv + sr0*3072 + zh*64;
    const unsigned short* kbase = qkv + ((long)zb*2048)*3072 + 1024 + zh*64;
    const unsigned short* vtb   = vt + (long)zb*2097152 + (long)zh*131072;

    s16x8 qf[2][2];
    #pragma unroll
    for(int qg=0;qg<2;qg++)
        #pragma unroll
        for(int kc=0;kc<2;kc++)
            qf[qg][kc] = *(const s16x8*)(qb + (qg*16+lr)*3072 + kc*32 + lg*8);

    float m0=-1e30f, m1=-1e30f, l0=0.f, l1=0.f;
    f32x4 oa[2][4];
    #pragma unroll
    for(int qg=0;qg<2;qg++)
        #pragma unroll
        for(int dt=0;dt<4;dt++) oa[qg][dt]=f32x4{0.f,0.f,0.f,0.f};

    char* Pw = (char*)&Pl[w][0];
    const int swz = (lr&7)<<4;

    for(int kv0=0; kv0<2048; kv0+=64){
        // ---- QK^T (S^T tiles: row=kpos, col=q) ----
        f32x4 s[2][4];
        #pragma unroll
        for(int kb=0;kb<4;kb++){
            const unsigned short* kr = kbase + (long)(kv0+kb*16+lr)*3072;
            s16x8 a0 = *(const s16x8*)(kr + lg*8);
            s16x8 a1 = *(const s16x8*)(kr + 32 + lg*8);
            #pragma unroll
            for(int qg=0;qg<2;qg++){
                f32x4 z4{0.f,0.f,0.f,0.f};
                z4 = __builtin_amdgcn_mfma_f32_16x16x32_bf16(a0, qf[qg][0], z4,0,0,0);
                s[qg][kb] = __builtin_amdgcn_mfma_f32_16x16x32_bf16(a1, qf[qg][1], z4,0,0,0);
            }
        }
        // ---- online softmax (per q-row = lane col lr; reduce across lg) ----
        #pragma unroll
        for(int qg=0;qg<2;qg++){
            float& m = qg? m1:m0;
            float& l = qg? l1:l0;
            f32x4 mx4 = fmax4(fmax4(s[qg][0],s[qg][1]),fmax4(s[qg][2],s[qg][3]));
            float bm = fmaxf(fmaxf(mx4[0],mx4[1]),fmaxf(mx4[2],mx4[3]));
            bm = fmaxf(bm, __shfl_xor(bm,16));
            bm = fmaxf(bm, __shfl_xor(bm,32));
            const float mn = fmaxf(m, bm);
            const float sc = __expf((m-mn)*ATT_SCALE);
            m = mn;
            float rs=0.f;
            #pragma unroll
            for(int kb=0;kb<4;kb++){
                f32x4 p;
                #pragma unroll
                for(int r=0;r<4;r++){ p[r]=__expf((s[qg][kb][r]-mn)*ATT_SCALE); rs+=p[r]; }
                s[qg][kb]=p;
            }
            rs += __shfl_xor(rs,16);
            rs += __shfl_xor(rs,32);
            l = l*sc + rs;
            #pragma unroll
            for(int dt=0;dt<4;dt++) oa[qg][dt] = oa[qg][dt]*sc;
            // pack P -> LDS (row q, col kpos; row-XOR swizzled)
            #pragma unroll
            for(int kb=0;kb<4;kb++){
                uint2 pw;
                pw.x = pk2t(s[qg][kb][0], s[qg][kb][1]);
                pw.y = pk2t(s[qg][kb][2], s[qg][kb][3]);
                *(uint2*)(Pw + (qg*16+lr)*128 + ((kb*32+lg*8)^swz)) = pw;
            }
        }
        asm volatile("s_waitcnt lgkmcnt(0)" ::: "memory");
        // ---- PV: oa[qg][dt] += V^T @ P ----
        s16x8 pb0[2], pb1[2];
        #pragma unroll
        for(int qg=0;qg<2;qg++){
            pb0[qg] = *(const s16x8*)(Pw + (qg*16+lr)*128 + ((     lg*16)^swz));
            pb1[qg] = *(const s16x8*)(Pw + (qg*16+lr)*128 + ((64 + lg*16)^swz));
        }
        #pragma unroll
        for(int dt=0;dt<4;dt++){
            const unsigned short* vr = vtb + (dt*16+lr)*2048 + kv0;
            s16x8 v0 = *(const s16x8*)(vr + lg*8);
            s16x8 v1 = *(const s16x8*)(vr + 32 + lg*8);
            #pragma unroll
            for(int qg=0;qg<2;qg++){
                oa[qg][dt] = __builtin_amdgcn_mfma_f32_16x16x32_bf16(v0, pb0[qg], oa[qg][dt],0,0,0);
                oa[qg][dt] = __builtin_amdgcn_mfma_f32_16x16x32_bf16(v1, pb1[qg], oa[qg][dt],0,0,0);
            }
        }
    }
    // ---- epilogue: O^T[d][q] -> o[(sr0+q)][zh*64+d], normalized by 1/l ----
    #pragma unroll
    for(int qg=0;qg<2;qg++){
        const float inv = 1.f/(qg? l1:l0);
        #pragma unroll
        for(int dt=0;dt<4;dt++){
            uint2 st;
            st.x = pk2r(oa[qg][dt][0]*inv, oa[qg][dt][1]*inv);
            st.y = pk2r(oa[qg][dt][2]*inv, oa[qg][dt][3]*inv);
            *(uint2*)(o + (sr0+qg*16+lr)*1024 + zh*64 + dt*16 + lg*4) = st;
        }
    }
}

// ===========================================================================
// 8-phase 256x256 GEMM (T2+T3+T4+T5): A (M,K) bf16 rm, B (N,K) bf16 rm.
// ===========================================================================
template<bool OBF16,bool BIAS>
__global__ __launch_bounds__(512,2) void gemm8_k(
    const unsigned short* __restrict__ A,
    const unsigned short* __restrict__ B,
    const float* __restrict__ bias,
    void* __restrict__ Cp,
    int K,int lda,int ldb,int ldc)
{
    __shared__ __align__(16) char lds[131072];
    const int t=threadIdx.x, w=t>>6, lane=t&63;
    const int wr=w>>2, wc=w&3;
    const int lr=lane&15, lg=lane>>4;

    const int nwg = gridDim.x*gridDim.y;
    const int id  = blockIdx.y*gridDim.x + blockIdx.x;
    const int nid = (id&7)*(nwg>>3) + (id>>3);
    const long row0 = (long)(nid % gridDim.x)*256;
    const long col0 = (long)(nid / gridDim.x)*256;

    const int NT = K>>6;

    const int csw0 = (lg*16) ^ ((lr&7)<<4);
    const int aRow = (wr*64+lr)*128;
    const int bRow = (wc*32+lr)*128;

    const int sro = t>>3;
    const int sce = (((t&7) ^ ((t>>3)&7))<<3);

#define STAGE(gp, ld_, lb) do{ \
    const unsigned short* _g=(gp); char* _l=(lb); \
    gl16(_g + (long)sro*(ld_) + sce, _l + t*16); \
    gl16(_g + (long)(sro+64)*(ld_) + sce, _l + 8192 + t*16); }while(0)

#define LDA8(m,kk) (*(const s16x8*)(Ab_ + aRow + ((m)&3)*2048 + ((m)>>2)*16384 + ((kk)? (csw0^64):csw0)))
#define LDB8(n,kk) (*(const s16x8*)(Bb_ + bRow + ((n)&1)*2048 + ((n)>>1)*16384 + ((kk)? (csw0^64):csw0)))

    f32x4 acc[8][4];
    #pragma unroll
    for(int m=0;m<8;m++)
        #pragma unroll
        for(int n=0;n<4;n++) acc[m][n]=f32x4{0.f,0.f,0.f,0.f};

    STAGE(A + row0*lda,        lda, lds);
    STAGE(B + col0*ldb,        ldb, lds+65536);
    STAGE(A + (row0+128)*lda,  lda, lds+16384);
    STAGE(B + (col0+128)*ldb,  ldb, lds+65536+16384);
    STAGE(A + row0*lda + 64,   lda, lds+32768);
    STAGE(B + col0*ldb + 64,   ldb, lds+65536+32768);
    asm volatile("s_waitcnt vmcnt(4)" ::: "memory");
    __builtin_amdgcn_s_barrier();

    for(int tt=0; tt<NT; ++tt){
        char* Ab_ = lds + ((tt&1)<<15);
        char* Bb_ = lds + 65536 + ((tt&1)<<15);
        char* An  = lds + (((tt+1)&1)<<15);
        char* Bn  = lds + 65536 + (((tt+1)&1)<<15);
        const int k1=(tt+1)<<6, k2=(tt+2)<<6;
        s16x8 a[4][2], b01[2][2], b23[2][2];

        #pragma unroll
        for(int m=0;m<4;m++){ a[m][0]=LDA8(m,0); a[m][1]=LDA8(m,1); }
        #pragma unroll
        for(int n=0;n<2;n++){ b01[n][0]=LDB8(n,0); b01[n][1]=LDB8(n,1); }
        if(tt+1<NT) STAGE(A + (row0+128)*lda + k1, lda, An+16384);
        __builtin_amdgcn_s_barrier();
        __builtin_amdgcn_s_setprio(1);
        #pragma unroll
        for(int kk=0;kk<2;kk++)
            #pragma unroll
            for(int m=0;m<4;m++)
                #pragma unroll
                for(int n=0;n<2;n++)
                    acc[m][n]=__builtin_amdgcn_mfma_f32_16x16x32_bf16(a[m][kk],b01[n][kk],acc[m][n],0,0,0);
        __builtin_amdgcn_s_setprio(0);
        __builtin_amdgcn_s_barrier();

        #pragma unroll
        for(int n=0;n<2;n++){ b23[n][0]=LDB8(n+2,0); b23[n][1]=LDB8(n+2,1); }
        if(tt+1<NT) STAGE(B + (col0+128)*ldb + k1, ldb, Bn+16384);
        __builtin_amdgcn_s_barrier();
        __builtin_amdgcn_s_setprio(1);
        #pragma unroll
        for(int kk=0;kk<2;kk++)
            #pragma unroll
            for(int m=0;m<4;m++)
                #pragma unroll
                for(int n=0;n<2;n++)
                    acc[m][n+2]=__builtin_amdgcn_mfma_f32_16x16x32_bf16(a[m][kk],b23[n][kk],acc[m][n+2],0,0,0);
        __builtin_amdgcn_s_setprio(0);
        __builtin_amdgcn_s_barrier();

        #pragma unroll
        for(int m=0;m<4;m++){ a[m][0]=LDA8(m+4,0); a[m][1]=LDA8(m+4,1); }
        if(tt+2<NT) STAGE(A + row0*lda + k2, lda, Ab_);
        __builtin_amdgcn_s_barrier();
        __builtin_amdgcn_s_setprio(1);
        #pragma unroll
        for(int kk=0;kk<2;kk++)
            #pragma unroll
            for(int m=0;m<4;m++)
                #pragma unroll
                for(int n=0;n<2;n++)
                    acc[m+4][n]=__builtin_amdgcn_mfma_f32_16x16x32_bf16(a[m][kk],b01[n][kk],acc[m+4][n],0,0,0);
        __builtin_amdgcn_s_setprio(0);
        __builtin_amdgcn_s_barrier();

        if(tt+2<NT) STAGE(B + col0*ldb + k2, ldb, Bb_);
        __builtin_amdgcn_s_barrier();
        __builtin_amdgcn_s_setprio(1);
        #pragma unroll
        for(int kk=0;kk<2;kk++)
            #pragma unroll
            for(int m=0;m<4;m++)
                #pragma unroll
                for(int n=0;n<2;n++)
                    acc[m+4][n+2]=__builtin_amdgcn_mfma_f32_16x16x32_bf16(a[m][kk],b23[n][kk],acc[m+4][n+2],0,0,0);
        __builtin_amdgcn_s_setprio(0);
        if(tt+2<NT) asm volatile("s_waitcnt vmcnt(4)" ::: "memory");
        else        asm volatile("s_waitcnt vmcnt(0)" ::: "memory");
        __builtin_amdgcn_s_barrier();
    }

    #pragma unroll
    for(int m=0;m<8;m++){
        #pragma unroll
        for(int n=0;n<4;n++){
            #pragma unroll
            for(int rr=0;rr<4;rr++){
                const long grow = row0 + wr*64 + (m&3)*16 + (m>>2)*128 + lg*4 + rr;
                const long gcol = col0 + wc*32 + (n&1)*16 + (n>>1)*128 + lr;
                float vv = acc[m][n][rr];
                if constexpr(BIAS) vv += bias[gcol];
                if constexpr(OBF16) ((unsigned short*)Cp)[grow*(long)ldc+gcol]=f2bf(vv);
                else                ((float*)Cp)[grow*(long)ldc+gcol]=vv;
            }
        }
    }
#undef STAGE
#undef LDA8
#undef LDB8
}

// ---------------------------------------------------------------------------
__global__ __launch_bounds__(256) void gelu8_k(const unsigned short* __restrict__ gv,
                                               unsigned short* __restrict__ ff)
{
    const long total8 = (long)4096*4096/8;
    for(long i8=(long)blockIdx.x*256+threadIdx.x; i8<total8; i8+=(long)gridDim.x*256){
        const long idx=i8*8;
        const long r=idx>>12; const int c=(int)(idx&4095);
        s16x8 g8=*(const s16x8*)(gv + r*8192 + c);
        s16x8 v8=*(const s16x8*)(gv + r*8192 + 4096 + c);
        s16x8 o8;
        #pragma unroll
        for(int i=0;i<8;i++){
            float gg=bf2f((unsigned short)g8[i]);
            float vl=bf2f((unsigned short)v8[i]);
            float ge=0.5f*gg*(1.f+erff(gg*0.70710678118654752f));
            o8[i]=(short)f2bf(ge*vl);
        }
        *(s16x8*)(ff+idx)=o8;
    }
}

// ---------------------------------------------------------------------------
// bias concat: bqkv[l][0..3071] = [bq[l] | bk[l] | bv[l]]
// ---------------------------------------------------------------------------
__global__ __launch_bounds__(256) void cat3_k(const float* __restrict__ a,
    const float* __restrict__ b, const float* __restrict__ c,
    float* __restrict__ out)
{
    const int i = blockIdx.x*256+threadIdx.x;   // 4*3072
    const int l = i/3072, cc = i%3072;
    float v = (cc<1024)? a[l*1024+cc] : (cc<2048)? b[l*1024+cc-1024] : c[l*1024+cc-2048];
    out[i]=v;
}

// ---------------------------------------------------------------------------
// Fast 2-phase GEMM (m97 structure), 128-tile family.
// ---------------------------------------------------------------------------
template<int BM,int BN,int WN,bool BIAS,bool RES,bool OBF16,bool SCL,bool SWAP,bool GEGLU>
__global__ __launch_bounds__(256) void gemm_bt(
    const unsigned short* __restrict__ A,
    const unsigned short* __restrict__ B,
    const unsigned short* __restrict__ B2,
    const float* __restrict__ bias,
    const float* __restrict__ res,
    void* __restrict__ Cp,
    int K,int lda,int ldb,int ldc,
    long aSb,long aSh,long bSb,long bSh,long cSb,long cSh,int zH)
{
    constexpr int BK=64;
    constexpr int WM=4/WN, WTM=BM/WM, WTN=BN/WN;
    constexpr int FM=WTM/16, FN=WTN/16;
    constexpr int CA=BM/8, CB=BN/8;
    __shared__ __align__(16) unsigned short As[BM*BK];
    __shared__ __align__(16) unsigned short Bs[BN*BK*(GEGLU?2:1)];

    const int t=threadIdx.x, w=t>>6, lane=t&63;
    const int wr=w/WN, wc=w%WN;
    const int lr=lane&15, lg=lane>>4;
    const int z=blockIdx.z, zb=z/zH, zh=z%zH;
    const long row0 = SWAP ? (long)blockIdx.x*BM : (long)blockIdx.y*BM;
    const long col0 = SWAP ? (long)blockIdx.y*BN : (long)blockIdx.x*BN;

    const unsigned short* Ab = A + zb*aSb + zh*aSh;
    const unsigned short* Bb = B + zb*bSb + zh*bSh;

    const int lr8 = lane>>3;
    const int lc8 = (lane&7)<<3;

    f32x4 acc[FM][FN];
    f32x4 acc2[GEGLU?FM:1][GEGLU?FN:1];
    #pragma unroll
    for(int i=0;i<FM;i++)
        #pragma unroll
        for(int j=0;j<FN;j++){
            acc[i][j]=f32x4{0.f,0.f,0.f,0.f};
            if constexpr(GEGLU) acc2[i][j]=f32x4{0.f,0.f,0.f,0.f};
        }

    const int NT=K/BK;
    for(int kt=0;kt<NT;kt++){
        const int kb=kt*BK;
        #pragma unroll
        for(int cc=0;cc<CA/4;cc++){
            const int c=cc*4+w;
            gl16(Ab + (row0 + c*8 + lr8)*(long)lda + kb + lc8, (char*)As + c*1024);
        }
        #pragma unroll
        for(int cc=0;cc<CB/4;cc++){
            const int c=cc*4+w;
            gl16(Bb + (col0 + c*8 + lr8)*(long)ldb + kb + lc8, (char*)Bs + c*1024);
        }
        if constexpr(GEGLU){
            #pragma unroll
            for(int cc=0;cc<CB/4;cc++){
                const int c=cc*4+w;
                gl16(B2 + (col0 + c*8 + lr8)*(long)ldb + kb + lc8,
                     (char*)Bs + (CB + c)*1024);
            }
        }
        __syncthreads();
        const unsigned short* Arp = As + (wr*WTM+lr)*BK + lg*8;
        const unsigned short* Brp = Bs + (wc*WTN+lr)*BK + lg*8;
        #pragma unroll
        for(int kk=0;kk<2;kk++){
            s16x8 af[FM], bfv[FN], bf2[GEGLU?FN:1];
            #pragma unroll
            for(int i=0;i<FM;i++) af[i] = *(const s16x8*)(Arp + i*16*BK + kk*32);
            #pragma unroll
            for(int j=0;j<FN;j++) bfv[j]= *(const s16x8*)(Brp + j*16*BK + kk*32);
            if constexpr(GEGLU){
                #pragma unroll
                for(int j=0;j<FN;j++) bf2[j]=*(const s16x8*)(Brp + BN*BK + j*16*BK + kk*32);
            }
            #pragma unroll
            for(int i=0;i<FM;i++)
                #pragma unroll
                for(int j=0;j<FN;j++){
                    acc[i][j]=__builtin_amdgcn_mfma_f32_16x16x32_bf16(af[i],bfv[j],acc[i][j],0,0,0);
                    if constexpr(GEGLU)
                        acc2[i][j]=__builtin_amdgcn_mfma_f32_16x16x32_bf16(af[i],bf2[j],acc2[i][j],0,0,0);
                }
        }
        __syncthreads();
    }
    #pragma unroll
    for(int i=0;i<FM;i++){
        #pragma unroll
        for(int j=0;j<FN;j++){
            #pragma unroll
            for(int r=0;r<4;r++){
                const long grow = row0 + wr*WTM + i*16 + lg*4 + r;
                const long gcol = col0 + wc*WTN + j*16 + lr;
                if constexpr(GEGLU){
                    float g  = acc[i][j][r]  + bias[gcol];
                    float vl = acc2[i][j][r] + bias[gcol+4096];
                    float ge = 0.5f*g*(1.f+erff(g*0.70710678118654752f));
                    ((unsigned short*)Cp)[grow*ldc+gcol] = f2bf(ge*vl);
                } else {
                    float vv=acc[i][j][r];
                    if constexpr(SCL)  vv*=ATT_SCALE;
                    if constexpr(BIAS) vv+=bias[gcol];
                    if constexpr(RES)  vv+=res[grow*ldc+gcol];
                    const long cidx = zb*cSb + zh*cSh + grow*ldc + gcol;
                    if constexpr(OBF16) ((unsigned short*)Cp)[cidx]=f2bf(vv);
                    else                ((float*)Cp)[cidx]=vv;
                }
            }
        }
    }
}

// ---------------------------------------------------------------------------
template<bool IN32>
__global__ __launch_bounds__(256) void tr_k(const void* __restrict__ in,
    unsigned short* __restrict__ out, int ldin, int ldout,
    long inZb, long inZh, long outZb, long outZh, int zH)
{
    __shared__ unsigned short tl[64][68];
    const int t=threadIdx.x;
    const int z=blockIdx.z, zb=z/zH, zh=z%zH;
    const long ib=(long)blockIdx.x*64*ldin + (long)blockIdx.y*64 + zb*inZb + zh*inZh;
    const long ob=(long)blockIdx.y*64*ldout + (long)blockIdx.x*64 + zb*outZb + zh*outZh;
    const int r0=t>>4, c0=(t&15)*4;
    #pragma unroll
    for(int p=0;p<4;p++){
        const int rr=r0+p*16;
        if constexpr(IN32){
            f32x4 v=*(const f32x4*)((const float*)in + ib + (long)rr*ldin + c0);
            #pragma unroll
            for(int i=0;i<4;i++) tl[c0+i][rr]=f2bf(v[i]);
        } else {
            s16x4 v=*(const s16x4*)((const unsigned short*)in + ib + (long)rr*ldin + c0);
            #pragma unroll
            for(int i=0;i<4;i++) tl[c0+i][rr]=(unsigned short)v[i];
        }
    }
    __syncthreads();
    #pragma unroll
    for(int p=0;p<4;p++){
        const int rr=r0+p*16;
        s16x4 o4;
        #pragma unroll
        for(int i=0;i<4;i++) o4[i]=(short)tl[rr][c0+i];
        *(s16x4*)(out + ob + (long)rr*ldout + c0)=o4;
    }
}

// ---------------------------------------------------------------------------
template<bool GATHER, bool OBF16>
__global__ __launch_bounds__(256) void ln_k(const float* __restrict__ in,
    const float* __restrict__ w, const float* __restrict__ b,
    void* __restrict__ out, const int* __restrict__ tok)
{
    const int row = blockIdx.x, t = threadIdx.x;
    const float* src;
    if constexpr (GATHER) src = in + (long)tok[row]*1024;
    else                  src = in + (long)row*1024;
    const int c = t*4;
    f32x4 xv = *(const f32x4*)(src + c);
    float s  = xv[0]+xv[1]+xv[2]+xv[3];
    float qq = xv[0]*xv[0]+xv[1]*xv[1]+xv[2]*xv[2]+xv[3]*xv[3];
    #pragma unroll
    for(int m=32;m;m>>=1){ s += __shfl_xor(s,m); qq += __shfl_xor(qq,m); }
    __shared__ float rs_[4], rq_[4];
    if((t&63)==0){ rs_[t>>6]=s; rq_[t>>6]=qq; }
    __syncthreads();
    s  = rs_[0]+rs_[1]+rs_[2]+rs_[3];
    qq = rq_[0]+rq_[1]+rq_[2]+rq_[3];
    const float mu = s*(1.f/1024.f);
    const float rstd = rsqrtf(qq*(1.f/1024.f)-mu*mu + 1e-5f);
    f32x4 wv = *(const f32x4*)(w+c), bv = *(const f32x4*)(b+c);
    if constexpr (OBF16){
        s16x4 ov;
        #pragma unroll
        for(int i=0;i<4;i++) ov[i]=(short)f2bf((xv[i]-mu)*rstd*wv[i]+bv[i]);
        *(s16x4*)((unsigned short*)out + (long)row*1024 + c) = ov;
    } else {
        f32x4 ov;
        #pragma unroll
        for(int i=0;i<4;i++) ov[i]=(xv[i]-mu)*rstd*wv[i]+bv[i];
        *(f32x4*)((float*)out + (long)row*1024 + c) = ov;
    }
}

// ---------------------------------------------------------------------------
// Slow fallback GEMM (f32 B transposed in-kernel) — tier-C logits only.
// ---------------------------------------------------------------------------
template<int BM,int BN,int WN,bool BIAS>
__global__ __launch_bounds__(256) void gemm_k(
    const unsigned short* __restrict__ A,
    const float* __restrict__ Bp,
    const float* __restrict__ bias,
    float* __restrict__ Cp,
    int K,int lda,int ldb,int ldc)
{
    constexpr int BK=64, PAD=24, LDS_=BK+PAD;
    constexpr int WM = 4/WN;
    constexpr int WTM = BM/WM, WTN = BN/WN;
    constexpr int FM = WTM/16, FN = WTN/16;
    __shared__ unsigned short As[BM*LDS_];
    __shared__ unsigned short Bs[BN*LDS_];

    const int t = threadIdx.x;
    const int w = t>>6, lane = t&63;
    const int wr = w / WN, wc = w % WN;
    const int lr = lane & 15, lg = lane >> 4;

    const long row0 = (long)blockIdx.y*BM;
    const long col0 = (long)blockIdx.x*BN;

    f32x4 acc[FM][FN];
    #pragma unroll
    for(int i=0;i<FM;i++)
        #pragma unroll
        for(int j=0;j<FN;j++) acc[i][j] = f32x4{0.f,0.f,0.f,0.f};

    const int NT = K/BK;
    for(int kt=0; kt<NT; ++kt){
        const int kb = kt*BK;
        {
            constexpr int PASS = BM*BK/(256*4);
            #pragma unroll
            for(int p=0;p<PASS;p++){
                int idx = (p*256+t)*4;
                int r = idx/BK, c = idx%BK;
                *(s16x4*)&As[r*LDS_+c] = *(const s16x4*)(A + (row0+r)*lda + kb + c);
            }
        }
        {
            constexpr int TPB = 256/BN;
            constexpr int KC  = BK/TPB;
            const int n = t % BN, k0 = (t/BN)*KC;
            #pragma unroll
            for(int j0=0;j0<KC;j0+=8){
                s16x8 pk;
                #pragma unroll
                for(int i=0;i<8;i++){
                    const long gk = (long)kb + k0 + j0 + i;
                    pk[i] = (short)f2bf(Bp[gk*ldb + col0 + n]);
                }
                *(s16x8*)&Bs[n*LDS_ + k0 + j0] = pk;
            }
        }
        __syncthreads();
        const unsigned short* Ar = &As[(wr*WTM + lr)*LDS_ + lg*8];
        const unsigned short* Br = &Bs[(wc*WTN + lr)*LDS_ + lg*8];
        #pragma unroll
        for(int kk=0;kk<BK/32;kk++){
            s16x8 af[FM], bfv[FN];
            #pragma unroll
            for(int i=0;i<FM;i++) af[i]  = *(const s16x8*)(Ar + i*16*LDS_ + kk*32);
            #pragma unroll
            for(int j=0;j<FN;j++) bfv[j] = *(const s16x8*)(Br + j*16*LDS_ + kk*32);
            #pragma unroll
            for(int i=0;i<FM;i++)
                #pragma unroll
                for(int j=0;j<FN;j++)
                    acc[i][j] = __builtin_amdgcn_mfma_f32_16x16x32_bf16(af[i],bfv[j],acc[i][j],0,0,0);
        }
        __syncthreads();
    }
    #pragma unroll
    for(int i=0;i<FM;i++){
        #pragma unroll
        for(int j=0;j<FN;j++){
            #pragma unroll
            for(int r=0;r<4;r++){
                long grow = row0 + wr*WTM + i*16 + lg*4 + r;
                long gcol = col0 + wc*WTN + j*16 + lr;
                float vv = acc[i][j][r];
                if constexpr (BIAS) vv += bias[gcol];
                Cp[grow*ldc + gcol] = vv;
            }
        }
    }
}

// ---------------------------------------------------------------------------
extern "C" void kernel_launch(void* const* d_in, const int* in_sizes, int n_in,
                              void* d_out, int out_size, void* d_ws, size_t ws_size,
                              hipStream_t stream)
{
    const int*   tokens  = (const int*)  d_in[0];
    const float* tok_emb = (const float*)d_in[1];
    const float* ln_e_w  = (const float*)d_in[2];
    const float* ln_e_b  = (const float*)d_in[3];
    const float* ln1_w   = (const float*)d_in[4];
    const float* ln1_b   = (const float*)d_in[5];
    const float* wq      = (const float*)d_in[6];
    const float* bq      = (const float*)d_in[7];
    const float* wk      = (const float*)d_in[8];
    const float* bk      = (const float*)d_in[9];
    const float* wv      = (const float*)d_in[10];
    const float* bv      = (const float*)d_in[11];
    const float* wo      = (const float*)d_in[12];
    const float* bo      = (const float*)d_in[13];
    const float* ln2_w   = (const float*)d_in[14];
    const float* ln2_b   = (const float*)d_in[15];
    const float* w1      = (const float*)d_in[16];
    const float* b1      = (const float*)d_in[17];
    const float* w2      = (const float*)d_in[18];
    const float* b2      = (const float*)d_in[19];
    const float* lnf_w   = (const float*)d_in[20];
    const float* lnf_b   = (const float*)d_in[21];
    const float* w_out   = (const float*)d_in[22];
    const float* b_out   = (const float*)d_in[23];

    const int D=1024;
    const long DD  = (long)D*D;
    const long WQKV_L = 3145728L;   // per-layer elems in wqkvT (3072*1024)

    unsigned short* gv8 = (unsigned short*)d_out;   // 64MB bf16 scratch (fast tier)

    unsigned short *wqkvT,*woT,*w1T,*w2T,*woutT=nullptr;
    float *x,*bqkv;
    unsigned short *h,*qkv,*vt,*o,*ff;
    bool fastTier;
    if (ws_size >= 301989888ull){
        char* p=(char*)d_ws;
        wqkvT=(unsigned short*)(p);                 // 25165824
        woT  =(unsigned short*)(p+25165824);        // 8388608
        w1T  =(unsigned short*)(p+33554432);        // 67108864
        w2T  =(unsigned short*)(p+100663296);       // 33554432
        woutT=(unsigned short*)(p+134217728);       // 65536000 (ends 199753728)
        x    =(float*)(p+201326592);                // 16777216
        h    =(unsigned short*)(p+218103808);       // 8388608
        qkv  =(unsigned short*)(p+226492416);       // 25165824
        vt   =(unsigned short*)(p+251658240);       // 8388608
        o    =(unsigned short*)(p+260046848);       // 8388608
        ff   =(unsigned short*)(p+268435456);       // 33554432 (ends 301989888)
        bqkv =(float*)((char*)d_out + 134217728);   // 49152, in d_out past gv8;
                                                    // rewritten by cat3_k every launch
        fastTier=true;
    } else {
        char* p=(char*)d_out;
        qkv  =(unsigned short*)(p);                 // 25165824
        bqkv =(float*)(p+25165824);                 // 49152
        wqkvT=(unsigned short*)(p+268435456);       // 25165824
        woT  =(unsigned short*)(p+293601280);       // 8388608
        w1T  =(unsigned short*)(p+301989888);       // 67108864
        w2T  =(unsigned short*)(p+369098752);       // 33554432
        x    =(float*)(p+402653184);
        vt   =(unsigned short*)(p+444596224);
        o    =(unsigned short*)(p+452984832);
        ff   =(unsigned short*)(p+461373440);
        h    =(unsigned short*)d_ws;
        fastTier=false;
    }

    const dim3 blk(256,1,1), blk8(512,1,1);

    // weight transposes: f32 (K,N) -> bf16 (N,K); q/k/v interleaved per layer
    tr_k<true><<<dim3(16,16,4), blk,0,stream>>>(wq, wqkvT,           1024,1024, DD,0, WQKV_L,0, 1);
    tr_k<true><<<dim3(16,16,4), blk,0,stream>>>(wk, wqkvT+1048576,   1024,1024, DD,0, WQKV_L,0, 1);
    tr_k<true><<<dim3(16,16,4), blk,0,stream>>>(wv, wqkvT+2097152,   1024,1024, DD,0, WQKV_L,0, 1);
    tr_k<true><<<dim3(16,16,4), blk,0,stream>>>(wo, woT, 1024,1024, DD,0, DD,0, 1);
    tr_k<true><<<dim3(16,128,4),blk,0,stream>>>(w1, w1T, 8192,1024, 8388608L,0, 8388608L,0, 1);
    tr_k<true><<<dim3(64,16,4), blk,0,stream>>>(w2, w2T, 1024,4096, 4194304L,0, 4194304L,0, 1);
    if (fastTier)
        tr_k<true><<<dim3(16,500,1),blk,0,stream>>>(w_out, woutT, 32000,1024, 0,0, 0,0, 1);
    cat3_k<<<48,blk,0,stream>>>(bq, bk, bv, bqkv);

    ln_k<true,false><<<4096,blk,0,stream>>>(tok_emb, ln_e_w, ln_e_b, x, tokens);

    const dim3 g_d(8,32,1);

    for(int l=0;l<4;l++){
        ln_k<false,true><<<4096,blk,0,stream>>>(x, ln1_w+l*D, ln1_b+l*D, h, nullptr);
        // fused QKV: (4096 x 3072) = h @ wqkvT^T
        gemm8_k<true,true><<<dim3(16,12,1),blk8,0,stream>>>(
            h, wqkvT+l*WQKV_L, bqkv+l*3072, qkv, 1024, 1024,1024,3072);
        // v slice (cols 2048..3071) -> vt (b,h,64,2048)
        tr_k<false><<<dim3(32,1,32),blk,0,stream>>>(qkv+2048, vt, 3072,2048,
            2048L*3072,64, 2097152L,131072L, 16);
        // flash attention -> o
        flash_k<<<dim3(16,32,1),blk,0,stream>>>(qkv, vt, o);
        // x += o @ wo + bo
        gemm_bt<128,128,2,true,true,false,false,false,false><<<g_d,blk,0,stream>>>(
            o, woT+l*DD, nullptr, bo+l*D, x, x, 1024, 1024,1024,1024, 0,0,0,0,0,0, 1);
        // FFN
        ln_k<false,true><<<4096,blk,0,stream>>>(x, ln2_w+l*D, ln2_b+l*D, h, nullptr);
        if (fastTier){
            gemm8_k<true,true><<<dim3(16,32,1),blk8,0,stream>>>(
                h, w1T+l*8388608L, b1+(long)l*8192, gv8, 1024, 1024,1024,8192);
            gelu8_k<<<2048,blk,0,stream>>>(gv8, ff);
        } else {
            gemm_bt<128,64,1,true,false,true,false,false,true><<<dim3(64,32,1),blk,0,stream>>>(
                h, w1T+l*8388608L, w1T+l*8388608L+4194304L, b1+(long)l*8192, nullptr, ff,
                1024, 1024,1024,4096, 0,0,0,0,0,0, 1);
        }
        gemm_bt<128,128,2,true,true,false,false,false,false><<<g_d,blk,0,stream>>>(
            ff, w2T+l*4194304L, nullptr, b2+l*D, x, x, 4096, 4096,4096,1024, 0,0,0,0,0,0, 1);
    }

    ln_k<false,true><<<4096,blk,0,stream>>>(x, lnf_w, lnf_b, h, nullptr);

    if (fastTier){
        gemm8_k<false,true><<<dim3(16,125,1),blk8,0,stream>>>(
            h, woutT, b_out, (float*)d_out, 1024, 1024,1024,32000);
    } else {
        gemm_k<128,128,2,true><<<dim3(250,32,1),blk,0,stream>>>(
            h, w_out, b_out, (float*)d_out, 1024, 1024,32000,32000);
    }
}

// Round 6
// 1998.416 us; speedup vs baseline: 2.5159x; 1.0887x over previous
//
#include <hip/hip_runtime.h>

typedef __attribute__((ext_vector_type(8))) short s16x8;
typedef __attribute__((ext_vector_type(4))) short s16x4;
typedef __attribute__((ext_vector_type(4))) float f32x4;

__device__ __forceinline__ unsigned short f2bf(float f){
    union{float f;unsigned u;}v; v.f=f;
    unsigned u=v.u;
    unsigned r=(u+0x7fffu+((u>>16)&1u))>>16;
    return (unsigned short)r;
}
__device__ __forceinline__ float bf2f(unsigned short s){
    union{unsigned u;float f;}v; v.u=((unsigned)s)<<16; return v.f;
}
__device__ __forceinline__ unsigned pk2t(float a, float b){   // truncating bf16 pack
    return (__float_as_uint(a)>>16) | (__float_as_uint(b) & 0xffff0000u);
}
__device__ __forceinline__ unsigned pk2r(float a, float b){   // rounding bf16 pack
    return (unsigned)f2bf(a) | ((unsigned)f2bf(b)<<16);
}
__device__ __forceinline__ f32x4 fmax4(f32x4 a, f32x4 b){
    f32x4 r; r[0]=fmaxf(a[0],b[0]); r[1]=fmaxf(a[1],b[1]);
    r[2]=fmaxf(a[2],b[2]); r[3]=fmaxf(a[3],b[3]); return r;
}

__device__ __forceinline__ void gl16(const void* g, void* l){
    __builtin_amdgcn_global_load_lds(
        (const __attribute__((address_space(1))) void*)g,
        (__attribute__((address_space(3))) void*)l, 16, 0, 0);
}

#define ATT_SCALE 0.125f

// ===========================================================================
// Flash attention: qkv (B*S, 3072) bf16 [q|k|v], vt (B,H,64,2048) bf16.
// 4 waves/wg, 128 q-rows/wg (32/wave), KVBLK=64, online softmax, o bf16.
// V loads hoisted above softmax (latency hidden); setprio on MFMA clusters.
// ===========================================================================
__global__ __launch_bounds__(256) void flash_k(
    const unsigned short* __restrict__ qkv,
    const unsigned short* __restrict__ vt,
    unsigned short* __restrict__ o)
{
    __shared__ __align__(16) unsigned short Pl[4][2048];   // per-wave P 32x64
    const int t=threadIdx.x, w=t>>6, lane=t&63;
    const int lr=lane&15, lg=lane>>4;
    const int zb=blockIdx.y>>4, zh=blockIdx.y&15;
    const long sr0 = (long)zb*2048 + blockIdx.x*128 + w*32;
    const unsigned short* qb    = qkv + sr0*3072 + zh*64;
    const unsigned short* kbase = qkv + ((long)zb*2048)*3072 + 1024 + zh*64;
    const unsigned short* vtb   = vt + (long)zb*2097152 + (long)zh*131072;

    s16x8 qf[2][2];
    #pragma unroll
    for(int qg=0;qg<2;qg++)
        #pragma unroll
        for(int kc=0;kc<2;kc++)
            qf[qg][kc] = *(const s16x8*)(qb + (qg*16+lr)*3072 + kc*32 + lg*8);

    float m0=-1e30f, m1=-1e30f, l0=0.f, l1=0.f;
    f32x4 oa[2][4];
    #pragma unroll
    for(int qg=0;qg<2;qg++)
        #pragma unroll
        for(int dt=0;dt<4;dt++) oa[qg][dt]=f32x4{0.f,0.f,0.f,0.f};

    char* Pw = (char*)&Pl[w][0];
    const int swz = (lr&7)<<4;

    for(int kv0=0; kv0<2048; kv0+=64){
        // ---- QK^T (S^T tiles: row=kpos, col=q) ----
        f32x4 s[2][4];
        __builtin_amdgcn_s_setprio(1);
        #pragma unroll
        for(int kb=0;kb<4;kb++){
            const unsigned short* kr = kbase + (long)(kv0+kb*16+lr)*3072;
            s16x8 a0 = *(const s16x8*)(kr + lg*8);
            s16x8 a1 = *(const s16x8*)(kr + 32 + lg*8);
            #pragma unroll
            for(int qg=0;qg<2;qg++){
                f32x4 z4{0.f,0.f,0.f,0.f};
                z4 = __builtin_amdgcn_mfma_f32_16x16x32_bf16(a0, qf[qg][0], z4,0,0,0);
                s[qg][kb] = __builtin_amdgcn_mfma_f32_16x16x32_bf16(a1, qf[qg][1], z4,0,0,0);
            }
        }
        __builtin_amdgcn_s_setprio(0);
        // ---- V loads issued EARLY (hide L2 latency under softmax) ----
        s16x8 vreg[4][2];
        #pragma unroll
        for(int dt=0;dt<4;dt++){
            const unsigned short* vr = vtb + (dt*16+lr)*2048 + kv0;
            vreg[dt][0] = *(const s16x8*)(vr + lg*8);
            vreg[dt][1] = *(const s16x8*)(vr + 32 + lg*8);
        }
        // ---- online softmax (per q-row = lane col lr; reduce across lg) ----
        #pragma unroll
        for(int qg=0;qg<2;qg++){
            float& m = qg? m1:m0;
            float& l = qg? l1:l0;
            f32x4 mx4 = fmax4(fmax4(s[qg][0],s[qg][1]),fmax4(s[qg][2],s[qg][3]));
            float bm = fmaxf(fmaxf(mx4[0],mx4[1]),fmaxf(mx4[2],mx4[3]));
            bm = fmaxf(bm, __shfl_xor(bm,16));
            bm = fmaxf(bm, __shfl_xor(bm,32));
            const float mn = fmaxf(m, bm);
            const float sc = __expf((m-mn)*ATT_SCALE);
            m = mn;
            float rs=0.f;
            #pragma unroll
            for(int kb=0;kb<4;kb++){
                f32x4 p;
                #pragma unroll
                for(int r=0;r<4;r++){ p[r]=__expf((s[qg][kb][r]-mn)*ATT_SCALE); rs+=p[r]; }
                s[qg][kb]=p;
            }
            rs += __shfl_xor(rs,16);
            rs += __shfl_xor(rs,32);
            l = l*sc + rs;
            #pragma unroll
            for(int dt=0;dt<4;dt++) oa[qg][dt] = oa[qg][dt]*sc;
            // pack P -> LDS (row q, col kpos; row-XOR swizzled)
            #pragma unroll
            for(int kb=0;kb<4;kb++){
                uint2 pw;
                pw.x = pk2t(s[qg][kb][0], s[qg][kb][1]);
                pw.y = pk2t(s[qg][kb][2], s[qg][kb][3]);
                *(uint2*)(Pw + (qg*16+lr)*128 + ((kb*32+lg*8)^swz)) = pw;
            }
        }
        asm volatile("s_waitcnt lgkmcnt(0)" ::: "memory");
        // ---- PV: oa[qg][dt] += V^T @ P ----
        s16x8 pb0[2], pb1[2];
        #pragma unroll
        for(int qg=0;qg<2;qg++){
            pb0[qg] = *(const s16x8*)(Pw + (qg*16+lr)*128 + ((     lg*16)^swz));
            pb1[qg] = *(const s16x8*)(Pw + (qg*16+lr)*128 + ((64 + lg*16)^swz));
        }
        __builtin_amdgcn_s_setprio(1);
        #pragma unroll
        for(int dt=0;dt<4;dt++){
            #pragma unroll
            for(int qg=0;qg<2;qg++){
                oa[qg][dt] = __builtin_amdgcn_mfma_f32_16x16x32_bf16(vreg[dt][0], pb0[qg], oa[qg][dt],0,0,0);
                oa[qg][dt] = __builtin_amdgcn_mfma_f32_16x16x32_bf16(vreg[dt][1], pb1[qg], oa[qg][dt],0,0,0);
            }
        }
        __builtin_amdgcn_s_setprio(0);
    }
    // ---- epilogue: O^T[d][q] -> o[(sr0+q)][zh*64+d], normalized by 1/l ----
    #pragma unroll
    for(int qg=0;qg<2;qg++){
        const float inv = 1.f/(qg? l1:l0);
        #pragma unroll
        for(int dt=0;dt<4;dt++){
            uint2 st;
            st.x = pk2r(oa[qg][dt][0]*inv, oa[qg][dt][1]*inv);
            st.y = pk2r(oa[qg][dt][2]*inv, oa[qg][dt][3]*inv);
            *(uint2*)(o + (sr0+qg*16+lr)*1024 + zh*64 + dt*16 + lg*4) = st;
        }
    }
}

// ===========================================================================
// 8-phase 256x256 GEMM (T2+T3+T4+T5): A (M,K) bf16 rm, B (N,K) bf16 rm.
// GEGLU: B panel = 128 gate rows + 128 val rows (interleaved w1T layout);
//        epilogue writes gelu(gate)*val bf16 at logical col (col0/2 + ...).
// !OBF16 (f32 out): LDS-staged coalesced dwordx4 epilogue (+bias).
// ===========================================================================
template<bool OBF16,bool BIAS,bool GEGLU>
__global__ __launch_bounds__(512,2) void gemm8_k(
    const unsigned short* __restrict__ A,
    const unsigned short* __restrict__ B,
    const float* __restrict__ bias,
    void* __restrict__ Cp,
    int K,int lda,int ldb,int ldc)
{
    __shared__ __align__(16) char lds[131072];
    const int t=threadIdx.x, w=t>>6, lane=t&63;
    const int wr=w>>2, wc=w&3;
    const int lr=lane&15, lg=lane>>4;

    const int nwg = gridDim.x*gridDim.y;
    const int id  = blockIdx.y*gridDim.x + blockIdx.x;
    const int nid = (id&7)*(nwg>>3) + (id>>3);
    const long row0 = (long)(nid % gridDim.x)*256;
    const long col0 = (long)(nid / gridDim.x)*256;

    const int NT = K>>6;

    const int csw0 = (lg*16) ^ ((lr&7)<<4);
    const int aRow = (wr*64+lr)*128;
    const int bRow = (wc*32+lr)*128;

    const int sro = t>>3;
    const int sce = (((t&7) ^ ((t>>3)&7))<<3);

#define STAGE(gp, ld_, lb) do{ \
    const unsigned short* _g=(gp); char* _l=(lb); \
    gl16(_g + (long)sro*(ld_) + sce, _l + t*16); \
    gl16(_g + (long)(sro+64)*(ld_) + sce, _l + 8192 + t*16); }while(0)

#define LDA8(m,kk) (*(const s16x8*)(Ab_ + aRow + ((m)&3)*2048 + ((m)>>2)*16384 + ((kk)? (csw0^64):csw0)))
#define LDB8(n,kk) (*(const s16x8*)(Bb_ + bRow + ((n)&1)*2048 + ((n)>>1)*16384 + ((kk)? (csw0^64):csw0)))

    f32x4 acc[8][4];
    #pragma unroll
    for(int m=0;m<8;m++)
        #pragma unroll
        for(int n=0;n<4;n++) acc[m][n]=f32x4{0.f,0.f,0.f,0.f};

    STAGE(A + row0*lda,        lda, lds);
    STAGE(B + col0*ldb,        ldb, lds+65536);
    STAGE(A + (row0+128)*lda,  lda, lds+16384);
    STAGE(B + (col0+128)*ldb,  ldb, lds+65536+16384);
    STAGE(A + row0*lda + 64,   lda, lds+32768);
    STAGE(B + col0*ldb + 64,   ldb, lds+65536+32768);
    asm volatile("s_waitcnt vmcnt(4)" ::: "memory");
    __builtin_amdgcn_s_barrier();

    for(int tt=0; tt<NT; ++tt){
        char* Ab_ = lds + ((tt&1)<<15);
        char* Bb_ = lds + 65536 + ((tt&1)<<15);
        char* An  = lds + (((tt+1)&1)<<15);
        char* Bn  = lds + 65536 + (((tt+1)&1)<<15);
        const int k1=(tt+1)<<6, k2=(tt+2)<<6;
        s16x8 a[4][2], b01[2][2], b23[2][2];

        #pragma unroll
        for(int m=0;m<4;m++){ a[m][0]=LDA8(m,0); a[m][1]=LDA8(m,1); }
        #pragma unroll
        for(int n=0;n<2;n++){ b01[n][0]=LDB8(n,0); b01[n][1]=LDB8(n,1); }
        if(tt+1<NT) STAGE(A + (row0+128)*lda + k1, lda, An+16384);
        __builtin_amdgcn_s_barrier();
        __builtin_amdgcn_s_setprio(1);
        #pragma unroll
        for(int kk=0;kk<2;kk++)
            #pragma unroll
            for(int m=0;m<4;m++)
                #pragma unroll
                for(int n=0;n<2;n++)
                    acc[m][n]=__builtin_amdgcn_mfma_f32_16x16x32_bf16(a[m][kk],b01[n][kk],acc[m][n],0,0,0);
        __builtin_amdgcn_s_setprio(0);
        __builtin_amdgcn_s_barrier();

        #pragma unroll
        for(int n=0;n<2;n++){ b23[n][0]=LDB8(n+2,0); b23[n][1]=LDB8(n+2,1); }
        if(tt+1<NT) STAGE(B + (col0+128)*ldb + k1, ldb, Bn+16384);
        __builtin_amdgcn_s_barrier();
        __builtin_amdgcn_s_setprio(1);
        #pragma unroll
        for(int kk=0;kk<2;kk++)
            #pragma unroll
            for(int m=0;m<4;m++)
                #pragma unroll
                for(int n=0;n<2;n++)
                    acc[m][n+2]=__builtin_amdgcn_mfma_f32_16x16x32_bf16(a[m][kk],b23[n][kk],acc[m][n+2],0,0,0);
        __builtin_amdgcn_s_setprio(0);
        __builtin_amdgcn_s_barrier();

        #pragma unroll
        for(int m=0;m<4;m++){ a[m][0]=LDA8(m+4,0); a[m][1]=LDA8(m+4,1); }
        if(tt+2<NT) STAGE(A + row0*lda + k2, lda, Ab_);
        __builtin_amdgcn_s_barrier();
        __builtin_amdgcn_s_setprio(1);
        #pragma unroll
        for(int kk=0;kk<2;kk++)
            #pragma unroll
            for(int m=0;m<4;m++)
                #pragma unroll
                for(int n=0;n<2;n++)
                    acc[m+4][n]=__builtin_amdgcn_mfma_f32_16x16x32_bf16(a[m][kk],b01[n][kk],acc[m+4][n],0,0,0);
        __builtin_amdgcn_s_setprio(0);
        __builtin_amdgcn_s_barrier();

        if(tt+2<NT) STAGE(B + col0*ldb + k2, ldb, Bb_);
        __builtin_amdgcn_s_barrier();
        __builtin_amdgcn_s_setprio(1);
        #pragma unroll
        for(int kk=0;kk<2;kk++)
            #pragma unroll
            for(int m=0;m<4;m++)
                #pragma unroll
                for(int n=0;n<2;n++)
                    acc[m+4][n+2]=__builtin_amdgcn_mfma_f32_16x16x32_bf16(a[m][kk],b23[n][kk],acc[m+4][n+2],0,0,0);
        __builtin_amdgcn_s_setprio(0);
        if(tt+2<NT) asm volatile("s_waitcnt vmcnt(4)" ::: "memory");
        else        asm volatile("s_waitcnt vmcnt(0)" ::: "memory");
        __builtin_amdgcn_s_barrier();
    }

    if constexpr(GEGLU){
        // gate = acc[m][0..1] (panel rows 0..127), val = acc[m][2..3] (+128)
        const long hc0 = col0>>1;
        #pragma unroll
        for(int m=0;m<8;m++){
            #pragma unroll
            for(int n=0;n<2;n++){
                #pragma unroll
                for(int rr=0;rr<4;rr++){
                    const long grow = row0 + wr*64 + (m&3)*16 + (m>>2)*128 + lg*4 + rr;
                    const long g    = hc0 + wc*32 + n*16 + lr;
                    float gg = acc[m][n][rr]   + bias[g];
                    float vl = acc[m][n+2][rr] + bias[4096+g];
                    float ge = 0.5f*gg*(1.f+erff(gg*0.70710678118654752f));
                    ((unsigned short*)Cp)[grow*(long)ldc + g] = f2bf(ge*vl);
                }
            }
        }
    } else if constexpr(!OBF16){
        // LDS-staged coalesced f32 epilogue (two 128-row chunks)
        float* L = (float*)lds;
        const int lc4 = (t&63)*4;
        f32x4 bv{0.f,0.f,0.f,0.f};
        if constexpr(BIAS) bv = *(const f32x4*)(bias + col0 + lc4);
        #pragma unroll
        for(int ch=0; ch<2; ch++){
            __builtin_amdgcn_s_barrier();
            #pragma unroll
            for(int mm=0;mm<4;mm++){
                #pragma unroll
                for(int n=0;n<4;n++){
                    #pragma unroll
                    for(int rr=0;rr<4;rr++){
                        const int lrow = wr*64 + mm*16 + lg*4 + rr;
                        const int lcol = wc*32 + (n&1)*16 + (n>>1)*128 + lr;
                        L[lrow*256 + lcol] = acc[ch*4+mm][n][rr];
                    }
                }
            }
            __builtin_amdgcn_s_barrier();
            #pragma unroll
            for(int p=0;p<16;p++){
                const int lrow = p*8 + (t>>6);
                f32x4 v4 = *(const f32x4*)(L + lrow*256 + lc4);
                if constexpr(BIAS){ v4[0]+=bv[0]; v4[1]+=bv[1]; v4[2]+=bv[2]; v4[3]+=bv[3]; }
                *(f32x4*)((float*)Cp + (row0 + ch*128 + lrow)*(long)ldc + col0 + lc4) = v4;
            }
        }
    } else {
        #pragma unroll
        for(int m=0;m<8;m++){
            #pragma unroll
            for(int n=0;n<4;n++){
                #pragma unroll
                for(int rr=0;rr<4;rr++){
                    const long grow = row0 + wr*64 + (m&3)*16 + (m>>2)*128 + lg*4 + rr;
                    const long gcol = col0 + wc*32 + (n&1)*16 + (n>>1)*128 + lr;
                    float vv = acc[m][n][rr];
                    if constexpr(BIAS) vv += bias[gcol];
                    ((unsigned short*)Cp)[grow*(long)ldc+gcol]=f2bf(vv);
                }
            }
        }
    }
#undef STAGE
#undef LDA8
#undef LDB8
}

// ---------------------------------------------------------------------------
// bias concat: bqkv[l][0..3071] = [bq[l] | bk[l] | bv[l]]
// ---------------------------------------------------------------------------
__global__ __launch_bounds__(256) void cat3_k(const float* __restrict__ a,
    const float* __restrict__ b, const float* __restrict__ c,
    float* __restrict__ out)
{
    const int i = blockIdx.x*256+threadIdx.x;   // 4*3072
    const int l = i/3072, cc = i%3072;
    float v = (cc<1024)? a[l*1024+cc] : (cc<2048)? b[l*1024+cc-1024] : c[l*1024+cc-2048];
    out[i]=v;
}

// ---------------------------------------------------------------------------
// Fast 2-phase GEMM (m97 structure), 128-tile family.
// ---------------------------------------------------------------------------
template<int BM,int BN,int WN,bool BIAS,bool RES,bool OBF16,bool SCL,bool SWAP,bool GEGLU>
__global__ __launch_bounds__(256) void gemm_bt(
    const unsigned short* __restrict__ A,
    const unsigned short* __restrict__ B,
    const unsigned short* __restrict__ B2,
    const float* __restrict__ bias,
    const float* __restrict__ res,
    void* __restrict__ Cp,
    int K,int lda,int ldb,int ldc,
    long aSb,long aSh,long bSb,long bSh,long cSb,long cSh,int zH)
{
    constexpr int BK=64;
    constexpr int WM=4/WN, WTM=BM/WM, WTN=BN/WN;
    constexpr int FM=WTM/16, FN=WTN/16;
    constexpr int CA=BM/8, CB=BN/8;
    __shared__ __align__(16) unsigned short As[BM*BK];
    __shared__ __align__(16) unsigned short Bs[BN*BK*(GEGLU?2:1)];

    const int t=threadIdx.x, w=t>>6, lane=t&63;
    const int wr=w/WN, wc=w%WN;
    const int lr=lane&15, lg=lane>>4;
    const int z=blockIdx.z, zb=z/zH, zh=z%zH;
    const long row0 = SWAP ? (long)blockIdx.x*BM : (long)blockIdx.y*BM;
    const long col0 = SWAP ? (long)blockIdx.y*BN : (long)blockIdx.x*BN;

    const unsigned short* Ab = A + zb*aSb + zh*aSh;
    const unsigned short* Bb = B + zb*bSb + zh*bSh;

    const int lr8 = lane>>3;
    const int lc8 = (lane&7)<<3;

    f32x4 acc[FM][FN];
    f32x4 acc2[GEGLU?FM:1][GEGLU?FN:1];
    #pragma unroll
    for(int i=0;i<FM;i++)
        #pragma unroll
        for(int j=0;j<FN;j++){
            acc[i][j]=f32x4{0.f,0.f,0.f,0.f};
            if constexpr(GEGLU) acc2[i][j]=f32x4{0.f,0.f,0.f,0.f};
        }

    const int NT=K/BK;
    for(int kt=0;kt<NT;kt++){
        const int kb=kt*BK;
        #pragma unroll
        for(int cc=0;cc<CA/4;cc++){
            const int c=cc*4+w;
            gl16(Ab + (row0 + c*8 + lr8)*(long)lda + kb + lc8, (char*)As + c*1024);
        }
        #pragma unroll
        for(int cc=0;cc<CB/4;cc++){
            const int c=cc*4+w;
            gl16(Bb + (col0 + c*8 + lr8)*(long)ldb + kb + lc8, (char*)Bs + c*1024);
        }
        if constexpr(GEGLU){
            #pragma unroll
            for(int cc=0;cc<CB/4;cc++){
                const int c=cc*4+w;
                gl16(B2 + (col0 + c*8 + lr8)*(long)ldb + kb + lc8,
                     (char*)Bs + (CB + c)*1024);
            }
        }
        __syncthreads();
        const unsigned short* Arp = As + (wr*WTM+lr)*BK + lg*8;
        const unsigned short* Brp = Bs + (wc*WTN+lr)*BK + lg*8;
        #pragma unroll
        for(int kk=0;kk<2;kk++){
            s16x8 af[FM], bfv[FN], bf2[GEGLU?FN:1];
            #pragma unroll
            for(int i=0;i<FM;i++) af[i] = *(const s16x8*)(Arp + i*16*BK + kk*32);
            #pragma unroll
            for(int j=0;j<FN;j++) bfv[j]= *(const s16x8*)(Brp + j*16*BK + kk*32);
            if constexpr(GEGLU){
                #pragma unroll
                for(int j=0;j<FN;j++) bf2[j]=*(const s16x8*)(Brp + BN*BK + j*16*BK + kk*32);
            }
            #pragma unroll
            for(int i=0;i<FM;i++)
                #pragma unroll
                for(int j=0;j<FN;j++){
                    acc[i][j]=__builtin_amdgcn_mfma_f32_16x16x32_bf16(af[i],bfv[j],acc[i][j],0,0,0);
                    if constexpr(GEGLU)
                        acc2[i][j]=__builtin_amdgcn_mfma_f32_16x16x32_bf16(af[i],bf2[j],acc2[i][j],0,0,0);
                }
        }
        __syncthreads();
    }
    #pragma unroll
    for(int i=0;i<FM;i++){
        #pragma unroll
        for(int j=0;j<FN;j++){
            #pragma unroll
            for(int r=0;r<4;r++){
                const long grow = row0 + wr*WTM + i*16 + lg*4 + r;
                const long gcol = col0 + wc*WTN + j*16 + lr;
                if constexpr(GEGLU){
                    float g  = acc[i][j][r]  + bias[gcol];
                    float vl = acc2[i][j][r] + bias[gcol+4096];
                    float ge = 0.5f*g*(1.f+erff(g*0.70710678118654752f));
                    ((unsigned short*)Cp)[grow*ldc+gcol] = f2bf(ge*vl);
                } else {
                    float vv=acc[i][j][r];
                    if constexpr(SCL)  vv*=ATT_SCALE;
                    if constexpr(BIAS) vv+=bias[gcol];
                    if constexpr(RES)  vv+=res[grow*ldc+gcol];
                    const long cidx = zb*cSb + zh*cSh + grow*ldc + gcol;
                    if constexpr(OBF16) ((unsigned short*)Cp)[cidx]=f2bf(vv);
                    else                ((float*)Cp)[cidx]=vv;
                }
            }
        }
    }
}

// ---------------------------------------------------------------------------
// Tiled 64x64 transpose. REMAP: gate/val interleave for w1T (out-row space:
// r<4096 -> (r>>7)*256+(r&127); r>=4096 -> ((r-4096)>>7)*256+128+((r-4096)&127))
// ---------------------------------------------------------------------------
template<bool IN32, bool REMAP>
__global__ __launch_bounds__(256) void tr_k(const void* __restrict__ in,
    unsigned short* __restrict__ out, int ldin, int ldout,
    long inZb, long inZh, long outZb, long outZh, int zH)
{
    __shared__ unsigned short tl[64][68];
    const int t=threadIdx.x;
    const int z=blockIdx.z, zb=z/zH, zh=z%zH;
    const long ib=(long)blockIdx.x*64*ldin + (long)blockIdx.y*64 + zb*inZb + zh*inZh;
    long orow = (long)blockIdx.y*64;
    if constexpr(REMAP){
        orow = (orow < 4096) ? ((orow>>7)*256 + (orow&127))
                             : (((orow-4096)>>7)*256 + 128 + ((orow-4096)&127));
    }
    const long ob=orow*ldout + (long)blockIdx.x*64 + zb*outZb + zh*outZh;
    const int r0=t>>4, c0=(t&15)*4;
    #pragma unroll
    for(int p=0;p<4;p++){
        const int rr=r0+p*16;
        if constexpr(IN32){
            f32x4 v=*(const f32x4*)((const float*)in + ib + (long)rr*ldin + c0);
            #pragma unroll
            for(int i=0;i<4;i++) tl[c0+i][rr]=f2bf(v[i]);
        } else {
            s16x4 v=*(const s16x4*)((const unsigned short*)in + ib + (long)rr*ldin + c0);
            #pragma unroll
            for(int i=0;i<4;i++) tl[c0+i][rr]=(unsigned short)v[i];
        }
    }
    __syncthreads();
    #pragma unroll
    for(int p=0;p<4;p++){
        const int rr=r0+p*16;
        s16x4 o4;
        #pragma unroll
        for(int i=0;i<4;i++) o4[i]=(short)tl[rr][c0+i];
        *(s16x4*)(out + ob + (long)rr*ldout + c0)=o4;
    }
}

// ---------------------------------------------------------------------------
template<bool GATHER, bool OBF16>
__global__ __launch_bounds__(256) void ln_k(const float* __restrict__ in,
    const float* __restrict__ w, const float* __restrict__ b,
    void* __restrict__ out, const int* __restrict__ tok)
{
    const int row = blockIdx.x, t = threadIdx.x;
    const float* src;
    if constexpr (GATHER) src = in + (long)tok[row]*1024;
    else                  src = in + (long)row*1024;
    const int c = t*4;
    f32x4 xv = *(const f32x4*)(src + c);
    float s  = xv[0]+xv[1]+xv[2]+xv[3];
    float qq = xv[0]*xv[0]+xv[1]*xv[1]+xv[2]*xv[2]+xv[3]*xv[3];
    #pragma unroll
    for(int m=32;m;m>>=1){ s += __shfl_xor(s,m); qq += __shfl_xor(qq,m); }
    __shared__ float rs_[4], rq_[4];
    if((t&63)==0){ rs_[t>>6]=s; rq_[t>>6]=qq; }
    __syncthreads();
    s  = rs_[0]+rs_[1]+rs_[2]+rs_[3];
    qq = rq_[0]+rq_[1]+rq_[2]+rq_[3];
    const float mu = s*(1.f/1024.f);
    const float rstd = rsqrtf(qq*(1.f/1024.f)-mu*mu + 1e-5f);
    f32x4 wv = *(const f32x4*)(w+c), bv = *(const f32x4*)(b+c);
    if constexpr (OBF16){
        s16x4 ov;
        #pragma unroll
        for(int i=0;i<4;i++) ov[i]=(short)f2bf((xv[i]-mu)*rstd*wv[i]+bv[i]);
        *(s16x4*)((unsigned short*)out + (long)row*1024 + c) = ov;
    } else {
        f32x4 ov;
        #pragma unroll
        for(int i=0;i<4;i++) ov[i]=(xv[i]-mu)*rstd*wv[i]+bv[i];
        *(f32x4*)((float*)out + (long)row*1024 + c) = ov;
    }
}

// ---------------------------------------------------------------------------
// Slow fallback GEMM (f32 B transposed in-kernel) — tier-C logits only.
// ---------------------------------------------------------------------------
template<int BM,int BN,int WN,bool BIAS>
__global__ __launch_bounds__(256) void gemm_k(
    const unsigned short* __restrict__ A,
    const float* __restrict__ Bp,
    const float* __restrict__ bias,
    float* __restrict__ Cp,
    int K,int lda,int ldb,int ldc)
{
    constexpr int BK=64, PAD=24, LDS_=BK+PAD;
    constexpr int WM = 4/WN;
    constexpr int WTM = BM/WM, WTN = BN/WN;
    constexpr int FM = WTM/16, FN = WTN/16;
    __shared__ unsigned short As[BM*LDS_];
    __shared__ unsigned short Bs[BN*LDS_];

    const int t = threadIdx.x;
    const int w = t>>6, lane = t&63;
    const int wr = w / WN, wc = w % WN;
    const int lr = lane & 15, lg = lane >> 4;

    const long row0 = (long)blockIdx.y*BM;
    const long col0 = (long)blockIdx.x*BN;

    f32x4 acc[FM][FN];
    #pragma unroll
    for(int i=0;i<FM;i++)
        #pragma unroll
        for(int j=0;j<FN;j++) acc[i][j] = f32x4{0.f,0.f,0.f,0.f};

    const int NT = K/BK;
    for(int kt=0; kt<NT; ++kt){
        const int kb = kt*BK;
        {
            constexpr int PASS = BM*BK/(256*4);
            #pragma unroll
            for(int p=0;p<PASS;p++){
                int idx = (p*256+t)*4;
                int r = idx/BK, c = idx%BK;
                *(s16x4*)&As[r*LDS_+c] = *(const s16x4*)(A + (row0+r)*lda + kb + c);
            }
        }
        {
            constexpr int TPB = 256/BN;
            constexpr int KC  = BK/TPB;
            const int n = t % BN, k0 = (t/BN)*KC;
            #pragma unroll
            for(int j0=0;j0<KC;j0+=8){
                s16x8 pk;
                #pragma unroll
                for(int i=0;i<8;i++){
                    const long gk = (long)kb + k0 + j0 + i;
                    pk[i] = (short)f2bf(Bp[gk*ldb + col0 + n]);
                }
                *(s16x8*)&Bs[n*LDS_ + k0 + j0] = pk;
            }
        }
        __syncthreads();
        const unsigned short* Ar = &As[(wr*WTM + lr)*LDS_ + lg*8];
        const unsigned short* Br = &Bs[(wc*WTN + lr)*LDS_ + lg*8];
        #pragma unroll
        for(int kk=0;kk<BK/32;kk++){
            s16x8 af[FM], bfv[FN];
            #pragma unroll
            for(int i=0;i<FM;i++) af[i]  = *(const s16x8*)(Ar + i*16*LDS_ + kk*32);
            #pragma unroll
            for(int j=0;j<FN;j++) bfv[j] = *(const s16x8*)(Br + j*16*LDS_ + kk*32);
            #pragma unroll
            for(int i=0;i<FM;i++)
                #pragma unroll
                for(int j=0;j<FN;j++)
                    acc[i][j] = __builtin_amdgcn_mfma_f32_16x16x32_bf16(af[i],bfv[j],acc[i][j],0,0,0);
        }
        __syncthreads();
    }
    #pragma unroll
    for(int i=0;i<FM;i++){
        #pragma unroll
        for(int j=0;j<FN;j++){
            #pragma unroll
            for(int r=0;r<4;r++){
                long grow = row0 + wr*WTM + i*16 + lg*4 + r;
                long gcol = col0 + wc*WTN + j*16 + lr;
                float vv = acc[i][j][r];
                if constexpr (BIAS) vv += bias[gcol];
                Cp[grow*ldc + gcol] = vv;
            }
        }
    }
}

// ---------------------------------------------------------------------------
extern "C" void kernel_launch(void* const* d_in, const int* in_sizes, int n_in,
                              void* d_out, int out_size, void* d_ws, size_t ws_size,
                              hipStream_t stream)
{
    const int*   tokens  = (const int*)  d_in[0];
    const float* tok_emb = (const float*)d_in[1];
    const float* ln_e_w  = (const float*)d_in[2];
    const float* ln_e_b  = (const float*)d_in[3];
    const float* ln1_w   = (const float*)d_in[4];
    const float* ln1_b   = (const float*)d_in[5];
    const float* wq      = (const float*)d_in[6];
    const float* bq      = (const float*)d_in[7];
    const float* wk      = (const float*)d_in[8];
    const float* bk      = (const float*)d_in[9];
    const float* wv      = (const float*)d_in[10];
    const float* bv      = (const float*)d_in[11];
    const float* wo      = (const float*)d_in[12];
    const float* bo      = (const float*)d_in[13];
    const float* ln2_w   = (const float*)d_in[14];
    const float* ln2_b   = (const float*)d_in[15];
    const float* w1      = (const float*)d_in[16];
    const float* b1      = (const float*)d_in[17];
    const float* w2      = (const float*)d_in[18];
    const float* b2      = (const float*)d_in[19];
    const float* lnf_w   = (const float*)d_in[20];
    const float* lnf_b   = (const float*)d_in[21];
    const float* w_out   = (const float*)d_in[22];
    const float* b_out   = (const float*)d_in[23];

    const int D=1024;
    const long DD  = (long)D*D;
    const long WQKV_L = 3145728L;   // per-layer elems in wqkvT (3072*1024)

    unsigned short *wqkvT,*woT,*w1T,*w2T,*woutT=nullptr;
    float *x,*bqkv;
    unsigned short *h,*qkv,*vt,*o,*ff;
    bool fastTier;
    if (ws_size >= 301989888ull){
        char* p=(char*)d_ws;
        wqkvT=(unsigned short*)(p);                 // 25165824
        woT  =(unsigned short*)(p+25165824);        // 8388608
        w1T  =(unsigned short*)(p+33554432);        // 67108864
        w2T  =(unsigned short*)(p+100663296);       // 33554432
        woutT=(unsigned short*)(p+134217728);       // 65536000 (ends 199753728)
        x    =(float*)(p+201326592);                // 16777216
        h    =(unsigned short*)(p+218103808);       // 8388608
        qkv  =(unsigned short*)(p+226492416);       // 25165824
        vt   =(unsigned short*)(p+251658240);       // 8388608
        o    =(unsigned short*)(p+260046848);       // 8388608
        ff   =(unsigned short*)(p+268435456);       // 33554432 (ends 301989888)
        bqkv =(float*)((char*)d_out + 134217728);   // in d_out; rewritten by
                                                    // cat3_k every launch
        fastTier=true;
    } else {
        char* p=(char*)d_out;
        qkv  =(unsigned short*)(p);                 // 25165824
        bqkv =(float*)(p+25165824);                 // 49152
        wqkvT=(unsigned short*)(p+268435456);       // 25165824
        woT  =(unsigned short*)(p+293601280);       // 8388608
        w1T  =(unsigned short*)(p+301989888);       // 67108864
        w2T  =(unsigned short*)(p+369098752);       // 33554432
        x    =(float*)(p+402653184);
        vt   =(unsigned short*)(p+444596224);
        o    =(unsigned short*)(p+452984832);
        ff   =(unsigned short*)(p+461373440);
        h    =(unsigned short*)d_ws;
        fastTier=false;
    }

    const dim3 blk(256,1,1), blk8(512,1,1);

    // weight transposes: f32 (K,N) -> bf16 (N,K); q/k/v interleaved per layer
    tr_k<true,false><<<dim3(16,16,4), blk,0,stream>>>(wq, wqkvT,         1024,1024, DD,0, WQKV_L,0, 1);
    tr_k<true,false><<<dim3(16,16,4), blk,0,stream>>>(wk, wqkvT+1048576, 1024,1024, DD,0, WQKV_L,0, 1);
    tr_k<true,false><<<dim3(16,16,4), blk,0,stream>>>(wv, wqkvT+2097152, 1024,1024, DD,0, WQKV_L,0, 1);
    tr_k<true,false><<<dim3(16,16,4), blk,0,stream>>>(wo, woT, 1024,1024, DD,0, DD,0, 1);
    if (fastTier){
        // gate/val-interleaved layout for fused-GeGLU gemm8 epilogue
        tr_k<true,true><<<dim3(16,128,4),blk,0,stream>>>(w1, w1T, 8192,1024, 8388608L,0, 8388608L,0, 1);
        tr_k<true,false><<<dim3(16,500,1),blk,0,stream>>>(w_out, woutT, 32000,1024, 0,0, 0,0, 1);
    } else {
        tr_k<true,false><<<dim3(16,128,4),blk,0,stream>>>(w1, w1T, 8192,1024, 8388608L,0, 8388608L,0, 1);
    }
    tr_k<true,false><<<dim3(64,16,4), blk,0,stream>>>(w2, w2T, 1024,4096, 4194304L,0, 4194304L,0, 1);
    cat3_k<<<48,blk,0,stream>>>(bq, bk, bv, bqkv);

    ln_k<true,false><<<4096,blk,0,stream>>>(tok_emb, ln_e_w, ln_e_b, x, tokens);

    const dim3 g_d(8,32,1);

    for(int l=0;l<4;l++){
        ln_k<false,true><<<4096,blk,0,stream>>>(x, ln1_w+l*D, ln1_b+l*D, h, nullptr);
        // fused QKV: (4096 x 3072) = h @ wqkvT^T
        gemm8_k<true,true,false><<<dim3(16,12,1),blk8,0,stream>>>(
            h, wqkvT+l*WQKV_L, bqkv+l*3072, qkv, 1024, 1024,1024,3072);
        // v slice (cols 2048..3071) -> vt (b,h,64,2048)
        tr_k<false,false><<<dim3(32,1,32),blk,0,stream>>>(qkv+2048, vt, 3072,2048,
            2048L*3072,64, 2097152L,131072L, 16);
        // flash attention -> o
        flash_k<<<dim3(16,32,1),blk,0,stream>>>(qkv, vt, o);
        // x += o @ wo + bo
        gemm_bt<128,128,2,true,true,false,false,false,false><<<g_d,blk,0,stream>>>(
            o, woT+l*DD, nullptr, bo+l*D, x, x, 1024, 1024,1024,1024, 0,0,0,0,0,0, 1);
        // FFN
        ln_k<false,true><<<4096,blk,0,stream>>>(x, ln2_w+l*D, ln2_b+l*D, h, nullptr);
        if (fastTier){
            // FF1 + GeGLU fused: ff (4096 x 4096) bf16
            gemm8_k<true,true,true><<<dim3(16,32,1),blk8,0,stream>>>(
                h, w1T+l*8388608L, b1+(long)l*8192, ff, 1024, 1024,1024,4096);
        } else {
            gemm_bt<128,64,1,true,false,true,false,false,true><<<dim3(64,32,1),blk,0,stream>>>(
                h, w1T+l*8388608L, w1T+l*8388608L+4194304L, b1+(long)l*8192, nullptr, ff,
                1024, 1024,1024,4096, 0,0,0,0,0,0, 1);
        }
        gemm_bt<128,128,2,true,true,false,false,false,false><<<g_d,blk,0,stream>>>(
            ff, w2T+l*4194304L, nullptr, b2+l*D, x, x, 4096, 4096,4096,1024, 0,0,0,0,0,0, 1);
    }

    ln_k<false,true><<<4096,blk,0,stream>>>(x, lnf_w, lnf_b, h, nullptr);

    if (fastTier){
        gemm8_k<false,true,false><<<dim3(16,125,1),blk8,0,stream>>>(
            h, woutT, b_out, (float*)d_out, 1024, 1024,1024,32000);
    } else {
        gemm_k<128,128,2,true><<<dim3(250,32,1),blk,0,stream>>>(
            h, w_out, b_out, (float*)d_out, 1024, 1024,32000,32000);
    }
}

// Round 7
// 1955.576 us; speedup vs baseline: 2.5710x; 1.0219x over previous
//
#include <hip/hip_runtime.h>

typedef __attribute__((ext_vector_type(8))) short s16x8;
typedef __attribute__((ext_vector_type(4))) short s16x4;
typedef __attribute__((ext_vector_type(4))) float f32x4;

__device__ __forceinline__ unsigned short f2bf(float f){
    union{float f;unsigned u;}v; v.f=f;
    unsigned u=v.u;
    unsigned r=(u+0x7fffu+((u>>16)&1u))>>16;
    return (unsigned short)r;
}
__device__ __forceinline__ float bf2f(unsigned short s){
    union{unsigned u;float f;}v; v.u=((unsigned)s)<<16; return v.f;
}
__device__ __forceinline__ unsigned pk2t(float a, float b){
    return (__float_as_uint(a)>>16) | (__float_as_uint(b) & 0xffff0000u);
}
__device__ __forceinline__ unsigned pk2r(float a, float b){
    return (unsigned)f2bf(a) | ((unsigned)f2bf(b)<<16);
}
__device__ __forceinline__ f32x4 fmax4(f32x4 a, f32x4 b){
    f32x4 r; r[0]=fmaxf(a[0],b[0]); r[1]=fmaxf(a[1],b[1]);
    r[2]=fmaxf(a[2],b[2]); r[3]=fmaxf(a[3],b[3]); return r;
}

__device__ __forceinline__ void gl16(const void* g, void* l){
    __builtin_amdgcn_global_load_lds(
        (const __attribute__((address_space(1))) void*)g,
        (__attribute__((address_space(3))) void*)l, 16, 0, 0);
}

#define ATT_SCALE 0.125f

// ===========================================================================
// Flash attention (unchanged from R6).
// ===========================================================================
__global__ __launch_bounds__(256) void flash_k(
    const unsigned short* __restrict__ qkv,
    const unsigned short* __restrict__ vt,
    unsigned short* __restrict__ o)
{
    __shared__ __align__(16) unsigned short Pl[4][2048];
    const int t=threadIdx.x, w=t>>6, lane=t&63;
    const int lr=lane&15, lg=lane>>4;
    const int zb=blockIdx.y>>4, zh=blockIdx.y&15;
    const long sr0 = (long)zb*2048 + blockIdx.x*128 + w*32;
    const unsigned short* qb    = qkv + sr0*3072 + zh*64;
    const unsigned short* kbase = qkv + ((long)zb*2048)*3072 + 1024 + zh*64;
    const unsigned short* vtb   = vt + (long)zb*2097152 + (long)zh*131072;

    s16x8 qf[2][2];
    #pragma unroll
    for(int qg=0;qg<2;qg++)
        #pragma unroll
        for(int kc=0;kc<2;kc++)
            qf[qg][kc] = *(const s16x8*)(qb + (qg*16+lr)*3072 + kc*32 + lg*8);

    float m0=-1e30f, m1=-1e30f, l0=0.f, l1=0.f;
    f32x4 oa[2][4];
    #pragma unroll
    for(int qg=0;qg<2;qg++)
        #pragma unroll
        for(int dt=0;dt<4;dt++) oa[qg][dt]=f32x4{0.f,0.f,0.f,0.f};

    char* Pw = (char*)&Pl[w][0];
    const int swz = (lr&7)<<4;

    for(int kv0=0; kv0<2048; kv0+=64){
        f32x4 s[2][4];
        __builtin_amdgcn_s_setprio(1);
        #pragma unroll
        for(int kb=0;kb<4;kb++){
            const unsigned short* kr = kbase + (long)(kv0+kb*16+lr)*3072;
            s16x8 a0 = *(const s16x8*)(kr + lg*8);
            s16x8 a1 = *(const s16x8*)(kr + 32 + lg*8);
            #pragma unroll
            for(int qg=0;qg<2;qg++){
                f32x4 z4{0.f,0.f,0.f,0.f};
                z4 = __builtin_amdgcn_mfma_f32_16x16x32_bf16(a0, qf[qg][0], z4,0,0,0);
                s[qg][kb] = __builtin_amdgcn_mfma_f32_16x16x32_bf16(a1, qf[qg][1], z4,0,0,0);
            }
        }
        __builtin_amdgcn_s_setprio(0);
        s16x8 vreg[4][2];
        #pragma unroll
        for(int dt=0;dt<4;dt++){
            const unsigned short* vr = vtb + (dt*16+lr)*2048 + kv0;
            vreg[dt][0] = *(const s16x8*)(vr + lg*8);
            vreg[dt][1] = *(const s16x8*)(vr + 32 + lg*8);
        }
        #pragma unroll
        for(int qg=0;qg<2;qg++){
            float& m = qg? m1:m0;
            float& l = qg? l1:l0;
            f32x4 mx4 = fmax4(fmax4(s[qg][0],s[qg][1]),fmax4(s[qg][2],s[qg][3]));
            float bm = fmaxf(fmaxf(mx4[0],mx4[1]),fmaxf(mx4[2],mx4[3]));
            bm = fmaxf(bm, __shfl_xor(bm,16));
            bm = fmaxf(bm, __shfl_xor(bm,32));
            const float mn = fmaxf(m, bm);
            const float sc = __expf((m-mn)*ATT_SCALE);
            m = mn;
            float rs=0.f;
            #pragma unroll
            for(int kb=0;kb<4;kb++){
                f32x4 p;
                #pragma unroll
                for(int r=0;r<4;r++){ p[r]=__expf((s[qg][kb][r]-mn)*ATT_SCALE); rs+=p[r]; }
                s[qg][kb]=p;
            }
            rs += __shfl_xor(rs,16);
            rs += __shfl_xor(rs,32);
            l = l*sc + rs;
            #pragma unroll
            for(int dt=0;dt<4;dt++) oa[qg][dt] = oa[qg][dt]*sc;
            #pragma unroll
            for(int kb=0;kb<4;kb++){
                uint2 pw;
                pw.x = pk2t(s[qg][kb][0], s[qg][kb][1]);
                pw.y = pk2t(s[qg][kb][2], s[qg][kb][3]);
                *(uint2*)(Pw + (qg*16+lr)*128 + ((kb*32+lg*8)^swz)) = pw;
            }
        }
        asm volatile("s_waitcnt lgkmcnt(0)" ::: "memory");
        s16x8 pb0[2], pb1[2];
        #pragma unroll
        for(int qg=0;qg<2;qg++){
            pb0[qg] = *(const s16x8*)(Pw + (qg*16+lr)*128 + ((     lg*16)^swz));
            pb1[qg] = *(const s16x8*)(Pw + (qg*16+lr)*128 + ((64 + lg*16)^swz));
        }
        __builtin_amdgcn_s_setprio(1);
        #pragma unroll
        for(int dt=0;dt<4;dt++){
            #pragma unroll
            for(int qg=0;qg<2;qg++){
                oa[qg][dt] = __builtin_amdgcn_mfma_f32_16x16x32_bf16(vreg[dt][0], pb0[qg], oa[qg][dt],0,0,0);
                oa[qg][dt] = __builtin_amdgcn_mfma_f32_16x16x32_bf16(vreg[dt][1], pb1[qg], oa[qg][dt],0,0,0);
            }
        }
        __builtin_amdgcn_s_setprio(0);
    }
    #pragma unroll
    for(int qg=0;qg<2;qg++){
        const float inv = 1.f/(qg? l1:l0);
        #pragma unroll
        for(int dt=0;dt<4;dt++){
            uint2 st;
            st.x = pk2r(oa[qg][dt][0]*inv, oa[qg][dt][1]*inv);
            st.y = pk2r(oa[qg][dt][2]*inv, oa[qg][dt][3]*inv);
            *(uint2*)(o + (sr0+qg*16+lr)*1024 + zh*64 + dt*16 + lg*4) = st;
        }
    }
}

// ===========================================================================
// 8->4-barrier 256x256 GEMM: 2 super-phases/tt, 32-MFMA clusters.
// f32 epilogue: swizzled LDS stage + nontemporal coalesced stores.
// ===========================================================================
template<bool OBF16,bool BIAS,bool GEGLU>
__global__ __launch_bounds__(512,2) void gemm8_k(
    const unsigned short* __restrict__ A,
    const unsigned short* __restrict__ B,
    const float* __restrict__ bias,
    void* __restrict__ Cp,
    int K,int lda,int ldb,int ldc)
{
    __shared__ __align__(16) char lds[131072];
    const int t=threadIdx.x, w=t>>6, lane=t&63;
    const int wr=w>>2, wc=w&3;
    const int lr=lane&15, lg=lane>>4;

    const int nwg = gridDim.x*gridDim.y;
    const int id  = blockIdx.y*gridDim.x + blockIdx.x;
    const int nid = (id&7)*(nwg>>3) + (id>>3);
    const long row0 = (long)(nid % gridDim.x)*256;
    const long col0 = (long)(nid / gridDim.x)*256;

    const int NT = K>>6;

    const int csw0 = (lg*16) ^ ((lr&7)<<4);
    const int aRow = (wr*64+lr)*128;
    const int bRow = (wc*32+lr)*128;

    const int sro = t>>3;
    const int sce = (((t&7) ^ ((t>>3)&7))<<3);

#define STAGE(gp, ld_, lb) do{ \
    const unsigned short* _g=(gp); char* _l=(lb); \
    gl16(_g + (long)sro*(ld_) + sce, _l + t*16); \
    gl16(_g + (long)(sro+64)*(ld_) + sce, _l + 8192 + t*16); }while(0)

#define LDA8(m,kk) (*(const s16x8*)(Ab_ + aRow + ((m)&3)*2048 + ((m)>>2)*16384 + ((kk)? (csw0^64):csw0)))
#define LDB8(n,kk) (*(const s16x8*)(Bb_ + bRow + ((n)&1)*2048 + ((n)>>1)*16384 + ((kk)? (csw0^64):csw0)))

    f32x4 acc[8][4];
    #pragma unroll
    for(int m=0;m<8;m++)
        #pragma unroll
        for(int n=0;n<4;n++) acc[m][n]=f32x4{0.f,0.f,0.f,0.f};

    STAGE(A + row0*lda,        lda, lds);
    STAGE(B + col0*ldb,        ldb, lds+65536);
    STAGE(A + (row0+128)*lda,  lda, lds+16384);
    STAGE(B + (col0+128)*ldb,  ldb, lds+65536+16384);
    STAGE(A + row0*lda + 64,   lda, lds+32768);
    STAGE(B + col0*ldb + 64,   ldb, lds+65536+32768);
    asm volatile("s_waitcnt vmcnt(4)" ::: "memory");
    __builtin_amdgcn_s_barrier();

    for(int tt=0; tt<NT; ++tt){
        char* Ab_ = lds + ((tt&1)<<15);
        char* Bb_ = lds + 65536 + ((tt&1)<<15);
        char* An  = lds + (((tt+1)&1)<<15);
        char* Bn  = lds + 65536 + (((tt+1)&1)<<15);
        const int k1=(tt+1)<<6, k2=(tt+2)<<6;
        s16x8 a[4][2], b[4][2];

        // ---- super-phase 0: m0-3 x n0-3 ----
        #pragma unroll
        for(int m=0;m<4;m++){ a[m][0]=LDA8(m,0); a[m][1]=LDA8(m,1); }
        #pragma unroll
        for(int n=0;n<4;n++){ b[n][0]=LDB8(n,0); b[n][1]=LDB8(n,1); }
        if(tt+1<NT){
            STAGE(A + (row0+128)*lda + k1, lda, An+16384);   // A-hi(t+1)
            STAGE(B + (col0+128)*ldb + k1, ldb, Bn+16384);   // B-hi(t+1)
        }
        __builtin_amdgcn_s_barrier();
        __builtin_amdgcn_s_setprio(1);
        #pragma unroll
        for(int kk=0;kk<2;kk++)
            #pragma unroll
            for(int m=0;m<4;m++)
                #pragma unroll
                for(int n=0;n<4;n++)
                    acc[m][n]=__builtin_amdgcn_mfma_f32_16x16x32_bf16(a[m][kk],b[n][kk],acc[m][n],0,0,0);
        __builtin_amdgcn_s_setprio(0);
        __builtin_amdgcn_s_barrier();

        // ---- super-phase 1: m4-7 x n0-3 ----
        #pragma unroll
        for(int m=0;m<4;m++){ a[m][0]=LDA8(m+4,0); a[m][1]=LDA8(m+4,1); }
        if(tt+2<NT){
            STAGE(A + row0*lda + k2, lda, Ab_);              // A-lo(t+2)
            STAGE(B + col0*ldb + k2, ldb, Bb_);              // B-lo(t+2)
        }
        __builtin_amdgcn_s_barrier();
        __builtin_amdgcn_s_setprio(1);
        #pragma unroll
        for(int kk=0;kk<2;kk++)
            #pragma unroll
            for(int m=0;m<4;m++)
                #pragma unroll
                for(int n=0;n<4;n++)
                    acc[m+4][n]=__builtin_amdgcn_mfma_f32_16x16x32_bf16(a[m][kk],b[n][kk],acc[m+4][n],0,0,0);
        __builtin_amdgcn_s_setprio(0);
        if(tt+2<NT) asm volatile("s_waitcnt vmcnt(4)" ::: "memory");
        else        asm volatile("s_waitcnt vmcnt(0)" ::: "memory");
        __builtin_amdgcn_s_barrier();
    }

    if constexpr(GEGLU){
        const long hc0 = col0>>1;
        #pragma unroll
        for(int m=0;m<8;m++){
            #pragma unroll
            for(int n=0;n<2;n++){
                #pragma unroll
                for(int rr=0;rr<4;rr++){
                    const long grow = row0 + wr*64 + (m&3)*16 + (m>>2)*128 + lg*4 + rr;
                    const long g    = hc0 + wc*32 + n*16 + lr;
                    float gg = acc[m][n][rr]   + bias[g];
                    float vl = acc[m][n+2][rr] + bias[4096+g];
                    float ge = 0.5f*gg*(1.f+erff(gg*0.70710678118654752f));
                    ((unsigned short*)Cp)[grow*(long)ldc + g] = f2bf(ge*vl);
                }
            }
        }
    } else if constexpr(!OBF16){
        // swizzled LDS-staged coalesced f32 epilogue, nontemporal stores
        float* L = (float*)lds;
        const int lc4 = (t&63)<<2;
        f32x4 bv{0.f,0.f,0.f,0.f};
        if constexpr(BIAS) bv = *(const f32x4*)(bias + col0 + lc4);
        #pragma unroll
        for(int ch=0; ch<2; ch++){
            __builtin_amdgcn_s_barrier();
            #pragma unroll
            for(int mm=0;mm<4;mm++){
                #pragma unroll
                for(int n=0;n<4;n++){
                    #pragma unroll
                    for(int rr=0;rr<4;rr++){
                        const int lrow = wr*64 + mm*16 + lg*4 + rr;
                        const int lcol = wc*32 + (n&1)*16 + (n>>1)*128 + lr;
                        const int pc = ((((lcol>>2) ^ (lrow&7))<<2) | (lcol&3));
                        L[lrow*256 + pc] = acc[ch*4+mm][n][rr];
                    }
                }
            }
            __builtin_amdgcn_s_barrier();
            #pragma unroll
            for(int p=0;p<16;p++){
                const int lrow = p*8 + (t>>6);
                const int pc4 = (((lc4>>2) ^ (lrow&7))<<2);
                f32x4 v4 = *(const f32x4*)(L + lrow*256 + pc4);
                if constexpr(BIAS){ v4[0]+=bv[0]; v4[1]+=bv[1]; v4[2]+=bv[2]; v4[3]+=bv[3]; }
                __builtin_nontemporal_store(v4,
                    (f32x4*)((float*)Cp + (row0 + ch*128 + lrow)*(long)ldc + col0 + lc4));
            }
        }
    } else {
        #pragma unroll
        for(int m=0;m<8;m++){
            #pragma unroll
            for(int n=0;n<4;n++){
                #pragma unroll
                for(int rr=0;rr<4;rr++){
                    const long grow = row0 + wr*64 + (m&3)*16 + (m>>2)*128 + lg*4 + rr;
                    const long gcol = col0 + wc*32 + (n&1)*16 + (n>>1)*128 + lr;
                    float vv = acc[m][n][rr];
                    if constexpr(BIAS) vv += bias[gcol];
                    ((unsigned short*)Cp)[grow*(long)ldc+gcol]=f2bf(vv);
                }
            }
        }
    }
#undef STAGE
#undef LDA8
#undef LDB8
}

// ---------------------------------------------------------------------------
__global__ __launch_bounds__(256) void cat3_k(const float* __restrict__ a,
    const float* __restrict__ b, const float* __restrict__ c,
    float* __restrict__ out)
{
    const int i = blockIdx.x*256+threadIdx.x;
    const int l = i/3072, cc = i%3072;
    float v = (cc<1024)? a[l*1024+cc] : (cc<2048)? b[l*1024+cc-1024] : c[l*1024+cc-2048];
    out[i]=v;
}

// ---------------------------------------------------------------------------
// Fast 2-phase GEMM (m97 structure), 128-tile family (unchanged).
// ---------------------------------------------------------------------------
template<int BM,int BN,int WN,bool BIAS,bool RES,bool OBF16,bool SCL,bool SWAP,bool GEGLU>
__global__ __launch_bounds__(256) void gemm_bt(
    const unsigned short* __restrict__ A,
    const unsigned short* __restrict__ B,
    const unsigned short* __restrict__ B2,
    const float* __restrict__ bias,
    const float* __restrict__ res,
    void* __restrict__ Cp,
    int K,int lda,int ldb,int ldc,
    long aSb,long aSh,long bSb,long bSh,long cSb,long cSh,int zH)
{
    constexpr int BK=64;
    constexpr int WM=4/WN, WTM=BM/WM, WTN=BN/WN;
    constexpr int FM=WTM/16, FN=WTN/16;
    constexpr int CA=BM/8, CB=BN/8;
    __shared__ __align__(16) unsigned short As[BM*BK];
    __shared__ __align__(16) unsigned short Bs[BN*BK*(GEGLU?2:1)];

    const int t=threadIdx.x, w=t>>6, lane=t&63;
    const int wr=w/WN, wc=w%WN;
    const int lr=lane&15, lg=lane>>4;
    const int z=blockIdx.z, zb=z/zH, zh=z%zH;
    const long row0 = SWAP ? (long)blockIdx.x*BM : (long)blockIdx.y*BM;
    const long col0 = SWAP ? (long)blockIdx.y*BN : (long)blockIdx.x*BN;

    const unsigned short* Ab = A + zb*aSb + zh*aSh;
    const unsigned short* Bb = B + zb*bSb + zh*bSh;

    const int lr8 = lane>>3;
    const int lc8 = (lane&7)<<3;

    f32x4 acc[FM][FN];
    f32x4 acc2[GEGLU?FM:1][GEGLU?FN:1];
    #pragma unroll
    for(int i=0;i<FM;i++)
        #pragma unroll
        for(int j=0;j<FN;j++){
            acc[i][j]=f32x4{0.f,0.f,0.f,0.f};
            if constexpr(GEGLU) acc2[i][j]=f32x4{0.f,0.f,0.f,0.f};
        }

    const int NT=K/BK;
    for(int kt=0;kt<NT;kt++){
        const int kb=kt*BK;
        #pragma unroll
        for(int cc=0;cc<CA/4;cc++){
            const int c=cc*4+w;
            gl16(Ab + (row0 + c*8 + lr8)*(long)lda + kb + lc8, (char*)As + c*1024);
        }
        #pragma unroll
        for(int cc=0;cc<CB/4;cc++){
            const int c=cc*4+w;
            gl16(Bb + (col0 + c*8 + lr8)*(long)ldb + kb + lc8, (char*)Bs + c*1024);
        }
        if constexpr(GEGLU){
            #pragma unroll
            for(int cc=0;cc<CB/4;cc++){
                const int c=cc*4+w;
                gl16(B2 + (col0 + c*8 + lr8)*(long)ldb + kb + lc8,
                     (char*)Bs + (CB + c)*1024);
            }
        }
        __syncthreads();
        const unsigned short* Arp = As + (wr*WTM+lr)*BK + lg*8;
        const unsigned short* Brp = Bs + (wc*WTN+lr)*BK + lg*8;
        #pragma unroll
        for(int kk=0;kk<2;kk++){
            s16x8 af[FM], bfv[FN], bf2[GEGLU?FN:1];
            #pragma unroll
            for(int i=0;i<FM;i++) af[i] = *(const s16x8*)(Arp + i*16*BK + kk*32);
            #pragma unroll
            for(int j=0;j<FN;j++) bfv[j]= *(const s16x8*)(Brp + j*16*BK + kk*32);
            if constexpr(GEGLU){
                #pragma unroll
                for(int j=0;j<FN;j++) bf2[j]=*(const s16x8*)(Brp + BN*BK + j*16*BK + kk*32);
            }
            #pragma unroll
            for(int i=0;i<FM;i++)
                #pragma unroll
                for(int j=0;j<FN;j++){
                    acc[i][j]=__builtin_amdgcn_mfma_f32_16x16x32_bf16(af[i],bfv[j],acc[i][j],0,0,0);
                    if constexpr(GEGLU)
                        acc2[i][j]=__builtin_amdgcn_mfma_f32_16x16x32_bf16(af[i],bf2[j],acc2[i][j],0,0,0);
                }
        }
        __syncthreads();
    }
    #pragma unroll
    for(int i=0;i<FM;i++){
        #pragma unroll
        for(int j=0;j<FN;j++){
            #pragma unroll
            for(int r=0;r<4;r++){
                const long grow = row0 + wr*WTM + i*16 + lg*4 + r;
                const long gcol = col0 + wc*WTN + j*16 + lr;
                if constexpr(GEGLU){
                    float g  = acc[i][j][r]  + bias[gcol];
                    float vl = acc2[i][j][r] + bias[gcol+4096];
                    float ge = 0.5f*g*(1.f+erff(g*0.70710678118654752f));
                    ((unsigned short*)Cp)[grow*ldc+gcol] = f2bf(ge*vl);
                } else {
                    float vv=acc[i][j][r];
                    if constexpr(SCL)  vv*=ATT_SCALE;
                    if constexpr(BIAS) vv+=bias[gcol];
                    if constexpr(RES)  vv+=res[grow*ldc+gcol];
                    const long cidx = zb*cSb + zh*cSh + grow*ldc + gcol;
                    if constexpr(OBF16) ((unsigned short*)Cp)[cidx]=f2bf(vv);
                    else                ((float*)Cp)[cidx]=vv;
                }
            }
        }
    }
}

// ---------------------------------------------------------------------------
// Tiled 64x64 transpose, 16B vectorized stores (8 cols/thread).
// ---------------------------------------------------------------------------
template<bool IN32, bool REMAP>
__global__ __launch_bounds__(256) void tr_k(const void* __restrict__ in,
    unsigned short* __restrict__ out, int ldin, int ldout,
    long inZb, long inZh, long outZb, long outZh, int zH)
{
    __shared__ unsigned short tl[64][66];
    const int t=threadIdx.x;
    const int z=blockIdx.z, zb=z/zH, zh=z%zH;
    const long ib=(long)blockIdx.x*64*ldin + (long)blockIdx.y*64 + zb*inZb + zh*inZh;
    long orow = (long)blockIdx.y*64;
    if constexpr(REMAP){
        orow = (orow < 4096) ? ((orow>>7)*256 + (orow&127))
                             : (((orow-4096)>>7)*256 + 128 + ((orow-4096)&127));
    }
    const long ob=orow*ldout + (long)blockIdx.x*64 + zb*outZb + zh*outZh;
    const int r0=t>>3, c8=(t&7)*8;
    #pragma unroll
    for(int p=0;p<2;p++){
        const int rr=r0+p*32;
        if constexpr(IN32){
            f32x4 v0=*(const f32x4*)((const float*)in + ib + (long)rr*ldin + c8);
            f32x4 v1=*(const f32x4*)((const float*)in + ib + (long)rr*ldin + c8+4);
            #pragma unroll
            for(int i=0;i<4;i++){ tl[c8+i][rr]=f2bf(v0[i]); tl[c8+4+i][rr]=f2bf(v1[i]); }
        } else {
            s16x8 v=*(const s16x8*)((const unsigned short*)in + ib + (long)rr*ldin + c8);
            #pragma unroll
            for(int i=0;i<8;i++) tl[c8+i][rr]=(unsigned short)v[i];
        }
    }
    __syncthreads();
    #pragma unroll
    for(int p=0;p<2;p++){
        const int rr=r0+p*32;
        s16x8 o8;
        #pragma unroll
        for(int i=0;i<8;i++) o8[i]=(short)tl[rr][c8+i];
        *(s16x8*)(out + ob + (long)rr*ldout + c8)=o8;
    }
}

// ---------------------------------------------------------------------------
template<bool GATHER, bool OBF16>
__global__ __launch_bounds__(256) void ln_k(const float* __restrict__ in,
    const float* __restrict__ w, const float* __restrict__ b,
    void* __restrict__ out, const int* __restrict__ tok)
{
    const int row = blockIdx.x, t = threadIdx.x;
    const float* src;
    if constexpr (GATHER) src = in + (long)tok[row]*1024;
    else                  src = in + (long)row*1024;
    const int c = t*4;
    f32x4 xv = *(const f32x4*)(src + c);
    float s  = xv[0]+xv[1]+xv[2]+xv[3];
    float qq = xv[0]*xv[0]+xv[1]*xv[1]+xv[2]*xv[2]+xv[3]*xv[3];
    #pragma unroll
    for(int m=32;m;m>>=1){ s += __shfl_xor(s,m); qq += __shfl_xor(qq,m); }
    __shared__ float rs_[4], rq_[4];
    if((t&63)==0){ rs_[t>>6]=s; rq_[t>>6]=qq; }
    __syncthreads();
    s  = rs_[0]+rs_[1]+rs_[2]+rs_[3];
    qq = rq_[0]+rq_[1]+rq_[2]+rq_[3];
    const float mu = s*(1.f/1024.f);
    const float rstd = rsqrtf(qq*(1.f/1024.f)-mu*mu + 1e-5f);
    f32x4 wv = *(const f32x4*)(w+c), bv = *(const f32x4*)(b+c);
    if constexpr (OBF16){
        s16x4 ov;
        #pragma unroll
        for(int i=0;i<4;i++) ov[i]=(short)f2bf((xv[i]-mu)*rstd*wv[i]+bv[i]);
        *(s16x4*)((unsigned short*)out + (long)row*1024 + c) = ov;
    } else {
        f32x4 ov;
        #pragma unroll
        for(int i=0;i<4;i++) ov[i]=(xv[i]-mu)*rstd*wv[i]+bv[i];
        *(f32x4*)((float*)out + (long)row*1024 + c) = ov;
    }
}

// ---------------------------------------------------------------------------
// Slow fallback GEMM — tier-C logits only.
// ---------------------------------------------------------------------------
template<int BM,int BN,int WN,bool BIAS>
__global__ __launch_bounds__(256) void gemm_k(
    const unsigned short* __restrict__ A,
    const float* __restrict__ Bp,
    const float* __restrict__ bias,
    float* __restrict__ Cp,
    int K,int lda,int ldb,int ldc)
{
    constexpr int BK=64, PAD=24, LDS_=BK+PAD;
    constexpr int WM = 4/WN;
    constexpr int WTM = BM/WM, WTN = BN/WN;
    constexpr int FM = WTM/16, FN = WTN/16;
    __shared__ unsigned short As[BM*LDS_];
    __shared__ unsigned short Bs[BN*LDS_];

    const int t = threadIdx.x;
    const int w = t>>6, lane = t&63;
    const int wr = w / WN, wc = w % WN;
    const int lr = lane & 15, lg = lane >> 4;

    const long row0 = (long)blockIdx.y*BM;
    const long col0 = (long)blockIdx.x*BN;

    f32x4 acc[FM][FN];
    #pragma unroll
    for(int i=0;i<FM;i++)
        #pragma unroll
        for(int j=0;j<FN;j++) acc[i][j] = f32x4{0.f,0.f,0.f,0.f};

    const int NT = K/BK;
    for(int kt=0; kt<NT; ++kt){
        const int kb = kt*BK;
        {
            constexpr int PASS = BM*BK/(256*4);
            #pragma unroll
            for(int p=0;p<PASS;p++){
                int idx = (p*256+t)*4;
                int r = idx/BK, c = idx%BK;
                *(s16x4*)&As[r*LDS_+c] = *(const s16x4*)(A + (row0+r)*lda + kb + c);
            }
        }
        {
            constexpr int TPB = 256/BN;
            constexpr int KC  = BK/TPB;
            const int n = t % BN, k0 = (t/BN)*KC;
            #pragma unroll
            for(int j0=0;j0<KC;j0+=8){
                s16x8 pk;
                #pragma unroll
                for(int i=0;i<8;i++){
                    const long gk = (long)kb + k0 + j0 + i;
                    pk[i] = (short)f2bf(Bp[gk*ldb + col0 + n]);
                }
                *(s16x8*)&Bs[n*LDS_ + k0 + j0] = pk;
            }
        }
        __syncthreads();
        const unsigned short* Ar = &As[(wr*WTM + lr)*LDS_ + lg*8];
        const unsigned short* Br = &Bs[(wc*WTN + lr)*LDS_ + lg*8];
        #pragma unroll
        for(int kk=0;kk<BK/32;kk++){
            s16x8 af[FM], bfv[FN];
            #pragma unroll
            for(int i=0;i<FM;i++) af[i]  = *(const s16x8*)(Ar + i*16*LDS_ + kk*32);
            #pragma unroll
            for(int j=0;j<FN;j++) bfv[j] = *(const s16x8*)(Br + j*16*LDS_ + kk*32);
            #pragma unroll
            for(int i=0;i<FM;i++)
                #pragma unroll
                for(int j=0;j<FN;j++)
                    acc[i][j] = __builtin_amdgcn_mfma_f32_16x16x32_bf16(af[i],bfv[j],acc[i][j],0,0,0);
        }
        __syncthreads();
    }
    #pragma unroll
    for(int i=0;i<FM;i++){
        #pragma unroll
        for(int j=0;j<FN;j++){
            #pragma unroll
            for(int r=0;r<4;r++){
                long grow = row0 + wr*WTM + i*16 + lg*4 + r;
                long gcol = col0 + wc*WTN + j*16 + lr;
                float vv = acc[i][j][r];
                if constexpr (BIAS) vv += bias[gcol];
                Cp[grow*ldc + gcol] = vv;
            }
        }
    }
}

// ---------------------------------------------------------------------------
extern "C" void kernel_launch(void* const* d_in, const int* in_sizes, int n_in,
                              void* d_out, int out_size, void* d_ws, size_t ws_size,
                              hipStream_t stream)
{
    const int*   tokens  = (const int*)  d_in[0];
    const float* tok_emb = (const float*)d_in[1];
    const float* ln_e_w  = (const float*)d_in[2];
    const float* ln_e_b  = (const float*)d_in[3];
    const float* ln1_w   = (const float*)d_in[4];
    const float* ln1_b   = (const float*)d_in[5];
    const float* wq      = (const float*)d_in[6];
    const float* bq      = (const float*)d_in[7];
    const float* wk      = (const float*)d_in[8];
    const float* bk      = (const float*)d_in[9];
    const float* wv      = (const float*)d_in[10];
    const float* bv      = (const float*)d_in[11];
    const float* wo      = (const float*)d_in[12];
    const float* bo      = (const float*)d_in[13];
    const float* ln2_w   = (const float*)d_in[14];
    const float* ln2_b   = (const float*)d_in[15];
    const float* w1      = (const float*)d_in[16];
    const float* b1      = (const float*)d_in[17];
    const float* w2      = (const float*)d_in[18];
    const float* b2      = (const float*)d_in[19];
    const float* lnf_w   = (const float*)d_in[20];
    const float* lnf_b   = (const float*)d_in[21];
    const float* w_out   = (const float*)d_in[22];
    const float* b_out   = (const float*)d_in[23];

    const int D=1024;
    const long DD  = (long)D*D;
    const long WQKV_L = 3145728L;

    unsigned short *wqkvT,*woT,*w1T,*w2T,*woutT=nullptr;
    float *x,*bqkv;
    unsigned short *h,*qkv,*vt,*o,*ff;
    bool fastTier;
    if (ws_size >= 301989888ull){
        char* p=(char*)d_ws;
        wqkvT=(unsigned short*)(p);
        woT  =(unsigned short*)(p+25165824);
        w1T  =(unsigned short*)(p+33554432);
        w2T  =(unsigned short*)(p+100663296);
        woutT=(unsigned short*)(p+134217728);
        x    =(float*)(p+201326592);
        h    =(unsigned short*)(p+218103808);
        qkv  =(unsigned short*)(p+226492416);
        vt   =(unsigned short*)(p+251658240);
        o    =(unsigned short*)(p+260046848);
        ff   =(unsigned short*)(p+268435456);
        bqkv =(float*)((char*)d_out + 134217728);
        fastTier=true;
    } else {
        char* p=(char*)d_out;
        qkv  =(unsigned short*)(p);
        bqkv =(float*)(p+25165824);
        wqkvT=(unsigned short*)(p+268435456);
        woT  =(unsigned short*)(p+293601280);
        w1T  =(unsigned short*)(p+301989888);
        w2T  =(unsigned short*)(p+369098752);
        x    =(float*)(p+402653184);
        vt   =(unsigned short*)(p+444596224);
        o    =(unsigned short*)(p+452984832);
        ff   =(unsigned short*)(p+461373440);
        h    =(unsigned short*)d_ws;
        fastTier=false;
    }

    const dim3 blk(256,1,1), blk8(512,1,1);

    tr_k<true,false><<<dim3(16,16,4), blk,0,stream>>>(wq, wqkvT,         1024,1024, DD,0, WQKV_L,0, 1);
    tr_k<true,false><<<dim3(16,16,4), blk,0,stream>>>(wk, wqkvT+1048576, 1024,1024, DD,0, WQKV_L,0, 1);
    tr_k<true,false><<<dim3(16,16,4), blk,0,stream>>>(wv, wqkvT+2097152, 1024,1024, DD,0, WQKV_L,0, 1);
    tr_k<true,false><<<dim3(16,16,4), blk,0,stream>>>(wo, woT, 1024,1024, DD,0, DD,0, 1);
    if (fastTier){
        tr_k<true,true><<<dim3(16,128,4),blk,0,stream>>>(w1, w1T, 8192,1024, 8388608L,0, 8388608L,0, 1);
        tr_k<true,false><<<dim3(16,500,1),blk,0,stream>>>(w_out, woutT, 32000,1024, 0,0, 0,0, 1);
    } else {
        tr_k<true,false><<<dim3(16,128,4),blk,0,stream>>>(w1, w1T, 8192,1024, 8388608L,0, 8388608L,0, 1);
    }
    tr_k<true,false><<<dim3(64,16,4), blk,0,stream>>>(w2, w2T, 1024,4096, 4194304L,0, 4194304L,0, 1);
    cat3_k<<<48,blk,0,stream>>>(bq, bk, bv, bqkv);

    ln_k<true,false><<<4096,blk,0,stream>>>(tok_emb, ln_e_w, ln_e_b, x, tokens);

    const dim3 g_d(8,32,1);

    for(int l=0;l<4;l++){
        ln_k<false,true><<<4096,blk,0,stream>>>(x, ln1_w+l*D, ln1_b+l*D, h, nullptr);
        gemm8_k<true,true,false><<<dim3(16,12,1),blk8,0,stream>>>(
            h, wqkvT+l*WQKV_L, bqkv+l*3072, qkv, 1024, 1024,1024,3072);
        tr_k<false,false><<<dim3(32,1,32),blk,0,stream>>>(qkv+2048, vt, 3072,2048,
            2048L*3072,64, 2097152L,131072L, 16);
        flash_k<<<dim3(16,32,1),blk,0,stream>>>(qkv, vt, o);
        gemm_bt<128,128,2,true,true,false,false,false,false><<<g_d,blk,0,stream>>>(
            o, woT+l*DD, nullptr, bo+l*D, x, x, 1024, 1024,1024,1024, 0,0,0,0,0,0, 1);
        ln_k<false,true><<<4096,blk,0,stream>>>(x, ln2_w+l*D, ln2_b+l*D, h, nullptr);
        if (fastTier){
            gemm8_k<true,true,true><<<dim3(16,32,1),blk8,0,stream>>>(
                h, w1T+l*8388608L, b1+(long)l*8192, ff, 1024, 1024,1024,4096);
        } else {
            gemm_bt<128,64,1,true,false,true,false,false,true><<<dim3(64,32,1),blk,0,stream>>>(
                h, w1T+l*8388608L, w1T+l*8388608L+4194304L, b1+(long)l*8192, nullptr, ff,
                1024, 1024,1024,4096, 0,0,0,0,0,0, 1);
        }
        gemm_bt<128,128,2,true,true,false,false,false,false><<<g_d,blk,0,stream>>>(
            ff, w2T+l*4194304L, nullptr, b2+l*D, x, x, 4096, 4096,4096,1024, 0,0,0,0,0,0, 1);
    }

    ln_k<false,true><<<4096,blk,0,stream>>>(x, lnf_w, lnf_b, h, nullptr);

    if (fastTier){
        gemm8_k<false,true,false><<<dim3(16,125,1),blk8,0,stream>>>(
            h, woutT, b_out, (float*)d_out, 1024, 1024,1024,32000);
    } else {
        gemm_k<128,128,2,true><<<dim3(250,32,1),blk,0,stream>>>(
            h, w_out, b_out, (float*)d_out, 1024, 1024,32000,32000);
    }
}